// Round 1
// baseline (847.391 us; speedup 1.0000x reference)
//
#include <hip/hip_runtime.h>
#include <hip/hip_bf16.h>

#define Bn 16
#define Cc 64
#define Hh 128
#define Ww 128
#define NCH 80         // 8 q + 8 k + 64 v channels
#define HW (Hh*Ww)     // 16384

typedef unsigned short u16;
typedef unsigned int u32;

__device__ __forceinline__ float b2f(u16 v){
    union { u32 u; float f; } cv; cv.u = ((u32)v) << 16; return cv.f;
}
__device__ __forceinline__ u16 f2b(float f){
    union { u32 u; float f; } cv; cv.f = f;
    u32 u = cv.u;
    u32 r = (u + 0x7fff + ((u >> 16) & 1)) >> 16;   // round-to-nearest-even
    return (u16)r;
}
#define NEG_INF (-__builtin_inff())

// ---------------------------------------------------------------- P1: qkv
__global__ __launch_bounds__(256) void k_qkv(
    const float* __restrict__ x, const float* __restrict__ y,
    const float* __restrict__ qw, const float* __restrict__ qb,
    const float* __restrict__ kw, const float* __restrict__ kb,
    const float* __restrict__ vw, const float* __restrict__ vb,
    u16* __restrict__ qkv)
{
    int t = threadIdx.x;
    int p = blockIdx.x * 256 + t;          // global pixel id
    int b = p >> 14;
    int rem = p & 16383;
    const float* xb = x + (size_t)b*Cc*HW + rem;
    const float* yb = y + (size_t)b*Cc*HW + rem;

    float qa[8], ka[8], va[64];
    #pragma unroll
    for (int o=0;o<8;o++){ qa[o]=0.f; ka[o]=0.f; }
    #pragma unroll
    for (int o=0;o<64;o++) va[o]=0.f;

    for (int c=0;c<64;c++){
        float xc = xb[(size_t)c*HW];
        float yc = yb[(size_t)c*HW];
        #pragma unroll
        for (int o=0;o<8;o++){ qa[o] += qw[o*64+c]*xc; ka[o] += kw[o*64+c]*yc; }
        #pragma unroll
        for (int o=0;o<64;o++){ va[o] += vw[o*128+c]*xc + vw[o*128+64+c]*yc; }
    }
    u16* outp = qkv + (size_t)b*NCH*HW + rem;
    #pragma unroll
    for (int o=0;o<8;o++)  outp[(size_t)o*HW]      = f2b(qa[o]+qb[o]);
    #pragma unroll
    for (int o=0;o<8;o++)  outp[(size_t)(8+o)*HW]  = f2b(ka[o]+kb[o]);
    #pragma unroll
    for (int o=0;o<64;o++) outp[(size_t)(16+o)*HW] = f2b(va[o]+vb[o]);
}

// ------------------------------------------------ generic 128x128 bf16 plane transpose
__global__ __launch_bounds__(256) void k_tr(const u16* __restrict__ src, u16* __restrict__ dst)
{
    __shared__ u16 tile[64][65];
    int blk = blockIdx.x;
    int plane = blk >> 2, tq = blk & 3;
    int r0 = (tq >> 1) * 64, c0 = (tq & 1) * 64;
    const u16* s = src + (size_t)plane * HW;
    u16* d = dst + (size_t)plane * HW;
    int col = threadIdx.x & 63, rr = threadIdx.x >> 6;   // rr: 0..3
    #pragma unroll
    for (int k=0;k<16;k++){
        int r = k*4 + rr;
        tile[r][col] = s[(r0+r)*Ww + c0 + col];
    }
    __syncthreads();
    #pragma unroll
    for (int k=0;k<16;k++){
        int r = k*4 + rr;
        d[(c0+r)*Hh + r0 + col] = tile[col][r];
    }
}

// ---------------------------------------------------------------- P2: column pass
// block = (b, w). qkvT layout: [(b*80+ch)][w][h]
__global__ __launch_bounds__(256) void k_col(
    const u16* __restrict__ qkvT, u16* __restrict__ colT,
    float* __restrict__ mH, float* __restrict__ sH)
{
    __shared__ __align__(16) float q_s[8][128];
    __shared__ __align__(16) float k_s[8][128];
    __shared__ __align__(16) float v_s[64*129];
    __shared__ __align__(16) float p_s[128*132];

    int t = threadIdx.x;
    int b = blockIdx.x >> 7, w = blockIdx.x & 127;
    const u16* base = qkvT + (size_t)b*NCH*HW + w*Hh;

    for (int idx = t; idx < NCH*128; idx += 256){
        int ch = idx >> 7, i = idx & 127;
        float v = b2f(base[(size_t)ch*HW + i]);
        if (ch < 8)        q_s[ch][i] = v;
        else if (ch < 16)  k_s[ch-8][i] = v;
        else               v_s[(ch-16)*129 + i] = v;
    }
    __syncthreads();

    // ---- E = Q^T K  (rows: pixel h, cols: g), tile 4h x 16g per thread
    int tr = t >> 3, tc = t & 7;
    int h0 = tr*4, g0 = tc*16;
    float e[4][16];
    #pragma unroll
    for (int i=0;i<4;i++)
        #pragma unroll
        for (int j=0;j<16;j++) e[i][j]=0.f;

    #pragma unroll
    for (int o=0;o<8;o++){
        float qv[4], kv[16];
        #pragma unroll
        for (int i=0;i<4;i++) qv[i]=q_s[o][h0+i];
        #pragma unroll
        for (int j=0;j<16;j++) kv[j]=k_s[o][g0+j];
        #pragma unroll
        for (int i=0;i<4;i++)
            #pragma unroll
            for (int j=0;j<16;j++) e[i][j] += qv[i]*kv[j];
    }
    // diag mask (energy_H only)
    #pragma unroll
    for (int i=0;i<4;i++){
        int h = h0+i;
        if (h >= g0 && h < g0+16) e[i][h-g0] = NEG_INF;
    }
    // per-row max, exp, sum (local to column direction)
    #pragma unroll
    for (int i=0;i<4;i++){
        float m = e[i][0];
        #pragma unroll
        for (int j=1;j<16;j++) m = fmaxf(m, e[i][j]);
        m = fmaxf(m, __shfl_xor(m, 1));
        m = fmaxf(m, __shfl_xor(m, 2));
        m = fmaxf(m, __shfl_xor(m, 4));
        float s = 0.f;
        #pragma unroll
        for (int j=0;j<16;j++){ float pp = __expf(e[i][j]-m); e[i][j]=pp; s+=pp; }
        s += __shfl_xor(s, 1);
        s += __shfl_xor(s, 2);
        s += __shfl_xor(s, 4);
        if (tc == 0){
            int h = h0+i;
            mH[b*HW + h*Ww + w] = m;
            sH[b*HW + h*Ww + w] = s;
        }
    }
    // write p transposed: p_s[g][h]
    #pragma unroll
    for (int j=0;j<16;j++){
        int g = g0+j;
        float4 pv = make_float4(e[0][j], e[1][j], e[2][j], e[3][j]);
        *(float4*)&p_s[g*132 + h0] = pv;
    }
    __syncthreads();

    // ---- colpart[c][h] = sum_g v_s[c][g] * p_s[g][h]; tile 4c x 8h
    int ci = t & 15, hi = t >> 4;
    int c0 = ci*4, hh0 = hi*8;
    float acc[4][8];
    #pragma unroll
    for (int k=0;k<4;k++)
        #pragma unroll
        for (int j=0;j<8;j++) acc[k][j]=0.f;

    #pragma unroll 4
    for (int g=0; g<128; g++){
        float4 p0 = *(float4*)&p_s[g*132 + hh0];
        float4 p1 = *(float4*)&p_s[g*132 + hh0 + 4];
        float pj[8] = {p0.x,p0.y,p0.z,p0.w,p1.x,p1.y,p1.z,p1.w};
        float a0 = v_s[(c0+0)*129+g];
        float a1 = v_s[(c0+1)*129+g];
        float a2 = v_s[(c0+2)*129+g];
        float a3 = v_s[(c0+3)*129+g];
        #pragma unroll
        for (int j=0;j<8;j++){
            acc[0][j] += a0*pj[j];
            acc[1][j] += a1*pj[j];
            acc[2][j] += a2*pj[j];
            acc[3][j] += a3*pj[j];
        }
    }
    #pragma unroll
    for (int k=0;k<4;k++){
        int c = c0+k;
        uint4 pk;
        pk.x = (u32)f2b(acc[k][0]) | ((u32)f2b(acc[k][1])<<16);
        pk.y = (u32)f2b(acc[k][2]) | ((u32)f2b(acc[k][3])<<16);
        pk.z = (u32)f2b(acc[k][4]) | ((u32)f2b(acc[k][5])<<16);
        pk.w = (u32)f2b(acc[k][6]) | ((u32)f2b(acc[k][7])<<16);
        *(uint4*)&colT[((size_t)(b*64+c)*Ww + w)*Hh + hh0] = pk;
    }
}

// ---------------------------------------------------------------- P3: row pass + combine
// block = (b, h). qkv natural layout.
__global__ __launch_bounds__(256) void k_row(
    const u16* __restrict__ qkv, const u16* __restrict__ colpart,
    const float* __restrict__ mH, const float* __restrict__ sH,
    const float* __restrict__ x, const float* __restrict__ y,
    const float* __restrict__ gamma_p, float* __restrict__ out)
{
    __shared__ __align__(16) float q_s[8][128];   // [o][w]
    __shared__ __align__(16) float k_s[8][128];   // [o][u]
    __shared__ __align__(16) float v_s[64*129];   // [c][u]
    __shared__ __align__(16) float p_s[128*132];  // [u][w]
    __shared__ float fc_s[128], fr_s[128];

    int t = threadIdx.x;
    int b = blockIdx.x >> 7, h = blockIdx.x & 127;
    const u16* base = qkv + (size_t)b*NCH*HW + h*Ww;

    for (int idx = t; idx < NCH*128; idx += 256){
        int ch = idx >> 7, i = idx & 127;
        float v = b2f(base[(size_t)ch*HW + i]);
        if (ch < 8)        q_s[ch][i] = v;
        else if (ch < 16)  k_s[ch-8][i] = v;
        else               v_s[(ch-16)*129 + i] = v;
    }
    __syncthreads();

    int tr = t >> 3, tc = t & 7;
    int w0 = tr*4, u0 = tc*16;
    float e[4][16];
    #pragma unroll
    for (int i=0;i<4;i++)
        #pragma unroll
        for (int j=0;j<16;j++) e[i][j]=0.f;

    #pragma unroll
    for (int o=0;o<8;o++){
        float qv[4], kv[16];
        #pragma unroll
        for (int i=0;i<4;i++) qv[i]=q_s[o][w0+i];
        #pragma unroll
        for (int j=0;j<16;j++) kv[j]=k_s[o][u0+j];
        #pragma unroll
        for (int i=0;i<4;i++)
            #pragma unroll
            for (int j=0;j<16;j++) e[i][j] += qv[i]*kv[j];
    }
    int pixbase = b*HW + h*Ww;
    #pragma unroll
    for (int i=0;i<4;i++){
        int wp = w0+i;
        float m = e[i][0];
        #pragma unroll
        for (int j=1;j<16;j++) m = fmaxf(m, e[i][j]);
        m = fmaxf(m, __shfl_xor(m, 1));
        m = fmaxf(m, __shfl_xor(m, 2));
        m = fmaxf(m, __shfl_xor(m, 4));
        float mh = mH[pixbase + wp];
        float sh = sH[pixbase + wp];
        float mg = fmaxf(m, mh);
        float s = 0.f;
        #pragma unroll
        for (int j=0;j<16;j++){ float pp = __expf(e[i][j]-mg); e[i][j]=pp; s+=pp; }
        s += __shfl_xor(s, 1);
        s += __shfl_xor(s, 2);
        s += __shfl_xor(s, 4);
        float stot = sh*__expf(mh-mg) + s;
        if (tc == 0){
            fc_s[wp] = __expf(mh-mg)/stot;
            fr_s[wp] = 1.0f/stot;
        }
    }
    #pragma unroll
    for (int j=0;j<16;j++){
        int u = u0+j;
        float4 pv = make_float4(e[0][j], e[1][j], e[2][j], e[3][j]);
        *(float4*)&p_s[u*132 + w0] = pv;
    }
    __syncthreads();

    // rowpart[c][w] = sum_u v_s[c][u] * p_s[u][w]
    int ci = t & 15, wi = t >> 4;
    int c0 = ci*4, ww0 = wi*8;
    float acc[4][8];
    #pragma unroll
    for (int k=0;k<4;k++)
        #pragma unroll
        for (int j=0;j<8;j++) acc[k][j]=0.f;

    #pragma unroll 4
    for (int u=0; u<128; u++){
        float4 p0 = *(float4*)&p_s[u*132 + ww0];
        float4 p1 = *(float4*)&p_s[u*132 + ww0 + 4];
        float pj[8] = {p0.x,p0.y,p0.z,p0.w,p1.x,p1.y,p1.z,p1.w};
        float a0 = v_s[(c0+0)*129+u];
        float a1 = v_s[(c0+1)*129+u];
        float a2 = v_s[(c0+2)*129+u];
        float a3 = v_s[(c0+3)*129+u];
        #pragma unroll
        for (int j=0;j<8;j++){
            acc[0][j] += a0*pj[j];
            acc[1][j] += a1*pj[j];
            acc[2][j] += a2*pj[j];
            acc[3][j] += a3*pj[j];
        }
    }
    float gm = gamma_p[0];
    #pragma unroll
    for (int k=0;k<4;k++){
        int c = c0+k;
        size_t off = ((size_t)(b*64+c)*Hh + h)*Ww + ww0;
        uint4 cpv = *(const uint4*)&colpart[off];
        float cp[8];
        cp[0]=b2f((u16)(cpv.x&0xffff)); cp[1]=b2f((u16)(cpv.x>>16));
        cp[2]=b2f((u16)(cpv.y&0xffff)); cp[3]=b2f((u16)(cpv.y>>16));
        cp[4]=b2f((u16)(cpv.z&0xffff)); cp[5]=b2f((u16)(cpv.z>>16));
        cp[6]=b2f((u16)(cpv.w&0xffff)); cp[7]=b2f((u16)(cpv.w>>16));
        float4 x0 = *(const float4*)&x[off];
        float4 x1 = *(const float4*)&x[off+4];
        float4 y0 = *(const float4*)&y[off];
        float4 y1 = *(const float4*)&y[off+4];
        float xs[8] = {x0.x,x0.y,x0.z,x0.w,x1.x,x1.y,x1.z,x1.w};
        float ys[8] = {y0.x,y0.y,y0.z,y0.w,y1.x,y1.y,y1.z,y1.w};
        float res[8];
        #pragma unroll
        for (int j=0;j<8;j++){
            res[j] = gm*( cp[j]*fc_s[ww0+j] + acc[k][j]*fr_s[ww0+j] ) + xs[j] + ys[j];
        }
        *(float4*)&out[off]   = make_float4(res[0],res[1],res[2],res[3]);
        *(float4*)&out[off+4] = make_float4(res[4],res[5],res[6],res[7]);
    }
}

// ----------------------------------------------------------------
extern "C" void kernel_launch(void* const* d_in, const int* in_sizes, int n_in,
                              void* d_out, int out_size, void* d_ws, size_t ws_size,
                              hipStream_t stream)
{
    (void)in_sizes; (void)n_in; (void)out_size; (void)ws_size;
    const float* x  = (const float*)d_in[0];
    const float* y  = (const float*)d_in[1];
    const float* qw = (const float*)d_in[2];
    const float* qb = (const float*)d_in[3];
    const float* kw = (const float*)d_in[4];
    const float* kb = (const float*)d_in[5];
    const float* vw = (const float*)d_in[6];
    const float* vb = (const float*)d_in[7];
    const float* gm = (const float*)d_in[8];
    float* out = (float*)d_out;

    char* ws = (char*)d_ws;
    u16* qkv   = (u16*)(ws);                      // 41,943,040 B
    u16* qkvT  = (u16*)(ws + 41943040ull);        // 41,943,040 B
    u16* colT  = (u16*)(ws + 83886080ull);        // 33,554,432 B
    u16* colpart = qkvT;                          // alias: qkvT dead after k_col
    float* mH  = (float*)(ws + 117440512ull);     // 1,048,576 B
    float* sH  = (float*)(ws + 118489088ull);     // 1,048,576 B

    k_qkv<<<1024, 256, 0, stream>>>(x, y, qw, qb, kw, kb, vw, vb, qkv);
    k_tr <<<5120, 256, 0, stream>>>(qkv, qkvT);          // 1280 planes
    k_col<<<2048, 256, 0, stream>>>(qkvT, colT, mH, sH);
    k_tr <<<4096, 256, 0, stream>>>(colT, colpart);      // 1024 planes
    k_row<<<2048, 256, 0, stream>>>(qkv, colpart, mH, sH, x, y, gm, out);
}

// Round 2
// 386.728 us; speedup vs baseline: 2.1912x; 2.1912x over previous
//
#include <hip/hip_runtime.h>

#define NCH 80
#define HW 16384

typedef unsigned short u16;
typedef unsigned int u32;

__device__ __forceinline__ float b2f_lo(u32 pk){ union{u32 u; float f;} c; c.u = pk<<16; return c.f; }
__device__ __forceinline__ float b2f_hi(u32 pk){ union{u32 u; float f;} c; c.u = pk & 0xffff0000u; return c.f; }
__device__ __forceinline__ float b2f(u16 v){ union{u32 u; float f;} c; c.u = ((u32)v)<<16; return c.f; }
__device__ __forceinline__ u16 f2b(float f){
    union{u32 u; float f;} c; c.f = f;
    return (u16)((c.u + 0x7fff + ((c.u>>16)&1))>>16);
}
#define NEG_INF (-__builtin_inff())

// ---------------------------------------------------------------- P1: qkv (unchanged from R1)
__global__ __launch_bounds__(256) void k_qkv(
    const float* __restrict__ x, const float* __restrict__ y,
    const float* __restrict__ qw, const float* __restrict__ qb,
    const float* __restrict__ kw, const float* __restrict__ kb,
    const float* __restrict__ vw, const float* __restrict__ vb,
    u16* __restrict__ qkv)
{
    int t = threadIdx.x;
    int p = blockIdx.x * 256 + t;
    int b = p >> 14;
    int rem = p & 16383;
    const float* xb = x + (size_t)b*64*HW + rem;
    const float* yb = y + (size_t)b*64*HW + rem;

    float qa[8], ka[8], va[64];
    #pragma unroll
    for (int o=0;o<8;o++){ qa[o]=0.f; ka[o]=0.f; }
    #pragma unroll
    for (int o=0;o<64;o++) va[o]=0.f;

    for (int c=0;c<64;c++){
        float xc = xb[(size_t)c*HW];
        float yc = yb[(size_t)c*HW];
        #pragma unroll
        for (int o=0;o<8;o++){ qa[o] += qw[o*64+c]*xc; ka[o] += kw[o*64+c]*yc; }
        #pragma unroll
        for (int o=0;o<64;o++){ va[o] += vw[o*128+c]*xc + vw[o*128+64+c]*yc; }
    }
    u16* outp = qkv + (size_t)b*NCH*HW + rem;
    #pragma unroll
    for (int o=0;o<8;o++)  outp[(size_t)o*HW]      = f2b(qa[o]+qb[o]);
    #pragma unroll
    for (int o=0;o<8;o++)  outp[(size_t)(8+o)*HW]  = f2b(ka[o]+kb[o]);
    #pragma unroll
    for (int o=0;o<64;o++) outp[(size_t)(16+o)*HW] = f2b(va[o]+vb[o]);
}

// ------------------------------------------------ 128x128 bf16 plane transpose (unchanged)
__global__ __launch_bounds__(256) void k_tr(const u16* __restrict__ src, u16* __restrict__ dst)
{
    __shared__ u16 tile[64][65];
    int blk = blockIdx.x;
    int plane = blk >> 2, tq = blk & 3;
    int r0 = (tq >> 1) * 64, c0 = (tq & 1) * 64;
    const u16* s = src + (size_t)plane * HW;
    u16* d = dst + (size_t)plane * HW;
    int col = threadIdx.x & 63, rr = threadIdx.x >> 6;
    #pragma unroll
    for (int k=0;k<16;k++){
        int r = k*4 + rr;
        tile[r][col] = s[(r0+r)*128 + c0 + col];
    }
    __syncthreads();
    #pragma unroll
    for (int k=0;k<16;k++){
        int r = k*4 + rr;
        d[(c0+r)*128 + r0 + col] = tile[col][r];
    }
}

// ---------------------------------------------------------------- P2: column pass v2
// block = (b, w), 512 threads. qkvT layout: [(b*80+ch)][w][h]
__global__ __launch_bounds__(512, 4) void k_col(
    const u16* __restrict__ qkvT, u16* __restrict__ colT,
    float* __restrict__ mH, float* __restrict__ sH)
{
    __shared__ __align__(16) float q_s[8*128];   // [o][h]
    __shared__ __align__(16) float k_sw[8*128];  // [g][o ^ ((g>>3)&7)]  conflict-free reads
    __shared__ __align__(16) u32  v2_s[64*67];   // [c][gp] bf16-pair, pad 67 -> 2-way max
    __shared__ __align__(16) u32  p2_s[128*66];  // [h][gp ^ 2(h>>2&3)] bf16-pair

    int t = threadIdx.x;
    int b = blockIdx.x >> 7, w = blockIdx.x & 127;
    const u32* src = (const u32*)(qkvT + (size_t)b*NCH*HW + w*128);

    // ---- staging
    #pragma unroll
    for (int r=0;r<2;r++){
        int idx = t + r*512;                // 0..1023 : q/k channels
        int ch = idx >> 6, hp = idx & 63;
        u32 pk = src[ch*8192 + hp];
        int g0 = hp*2;
        if (ch < 8){
            *(float2*)&q_s[ch*128 + g0] = make_float2(b2f_lo(pk), b2f_hi(pk));
        } else {
            int o = ch - 8;
            k_sw[g0*8     + (o ^ ((g0>>3)&7))]     = b2f_lo(pk);
            k_sw[(g0+1)*8 + (o ^ (((g0+1)>>3)&7))] = b2f_hi(pk);
        }
    }
    #pragma unroll
    for (int r=0;r<8;r++){
        int idx = t + r*512;                // 0..4095 : v channels, keep bf16 pairs
        int c = idx >> 6, gp = idx & 63;
        v2_s[c*67 + gp] = src[(16+c)*8192 + gp];
    }
    __syncthreads();

    // ---- E = Q^T K : per-thread tile [4h][8g]
    int tr = t >> 4, tc = t & 15;           // tr 0..31, tc 0..15
    int h0 = tr*4, g0 = tc*8;
    float e[4][8];
    #pragma unroll
    for (int i=0;i<4;i++)
        #pragma unroll
        for (int j=0;j<8;j++) e[i][j] = 0.f;

    #pragma unroll
    for (int o=0;o<8;o++){
        float qv[4], kv[8];
        #pragma unroll
        for (int i=0;i<4;i++) qv[i] = q_s[o*128 + h0 + i];
        int kb = o ^ (tc & 7);
        #pragma unroll
        for (int j=0;j<8;j++) kv[j] = k_sw[(g0+j)*8 + kb];
        #pragma unroll
        for (int i=0;i<4;i++)
            #pragma unroll
            for (int j=0;j<8;j++) e[i][j] += qv[i]*kv[j];
    }
    // diag mask
    #pragma unroll
    for (int i=0;i<4;i++){
        int h = h0 + i;
        if ((h>>3) == tc) e[i][h&7] = NEG_INF;
    }
    // ---- softmax stats (local to column dir), pack p -> bf16 pairs into p2_s
    int f  = 2*(tr & 3);
    int Bb = (4*tc) ^ (f & 4);
    #pragma unroll
    for (int i=0;i<4;i++){
        int h = h0 + i;
        float m = e[i][0];
        #pragma unroll
        for (int j=1;j<8;j++) m = fmaxf(m, e[i][j]);
        m = fmaxf(m, __shfl_xor(m,1));
        m = fmaxf(m, __shfl_xor(m,2));
        m = fmaxf(m, __shfl_xor(m,4));
        m = fmaxf(m, __shfl_xor(m,8));
        float s = 0.f;
        #pragma unroll
        for (int j=0;j<8;j++){ float pp = __expf(e[i][j]-m); e[i][j]=pp; s += pp; }
        s += __shfl_xor(s,1);
        s += __shfl_xor(s,2);
        s += __shfl_xor(s,4);
        s += __shfl_xor(s,8);
        if (tc == 0){
            mH[b*HW + h*128 + w] = m;
            sH[b*HW + h*128 + w] = s;
        }
        u32 pk0 = (u32)f2b(e[i][0]) | ((u32)f2b(e[i][1])<<16);
        u32 pk1 = (u32)f2b(e[i][2]) | ((u32)f2b(e[i][3])<<16);
        u32 pk2 = (u32)f2b(e[i][4]) | ((u32)f2b(e[i][5])<<16);
        u32 pk3 = (u32)f2b(e[i][6]) | ((u32)f2b(e[i][7])<<16);
        bool sw = (f & 2) != 0;
        uint2 loPair = sw ? make_uint2(pk2, pk3) : make_uint2(pk0, pk1);
        uint2 hiPair = sw ? make_uint2(pk0, pk1) : make_uint2(pk2, pk3);
        *(uint2*)&p2_s[h*66 + Bb]     = loPair;
        *(uint2*)&p2_s[h*66 + Bb + 2] = hiPair;
    }
    __syncthreads();

    // ---- PV: colpart[c][h] = sum_g v[c][g] p[h][g], per-thread [4c][4h]
    int ci = t & 15, hq = t >> 4;           // ci 0..15, hq 0..31
    int c0 = 4*ci, hh0 = 4*hq;
    int fv = 2*(hq & 3);
    float acc[4][4];
    #pragma unroll
    for (int k=0;k<4;k++)
        #pragma unroll
        for (int i=0;i<4;i++) acc[k][i] = 0.f;

    #pragma unroll 8
    for (int gp=0; gp<64; gp++){
        int gpp = gp ^ fv;
        u32 pA = p2_s[(hh0+0)*66 + gpp];
        u32 pB = p2_s[(hh0+1)*66 + gpp];
        u32 pC = p2_s[(hh0+2)*66 + gpp];
        u32 pD = p2_s[(hh0+3)*66 + gpp];
        float pl[4] = {b2f_lo(pA), b2f_lo(pB), b2f_lo(pC), b2f_lo(pD)};
        float ph[4] = {b2f_hi(pA), b2f_hi(pB), b2f_hi(pC), b2f_hi(pD)};
        #pragma unroll
        for (int k=0;k<4;k++){
            u32 vv = v2_s[(c0+k)*67 + gp];
            float vl = b2f_lo(vv), vh = b2f_hi(vv);
            #pragma unroll
            for (int i=0;i<4;i++) acc[k][i] += vl*pl[i] + vh*ph[i];
        }
    }
    // ---- store colT[c][w][h] as 8B chunks (contiguous h)
    #pragma unroll
    for (int k=0;k<4;k++){
        uint2 st;
        st.x = (u32)f2b(acc[k][0]) | ((u32)f2b(acc[k][1])<<16);
        st.y = (u32)f2b(acc[k][2]) | ((u32)f2b(acc[k][3])<<16);
        *(uint2*)&colT[((size_t)(b*64 + c0 + k)*128 + w)*128 + hh0] = st;
    }
}

// ---------------------------------------------------------------- P3: row pass + combine v2
// block = (b, h), 512 threads. qkv natural layout.
__global__ __launch_bounds__(512, 4) void k_row(
    const u16* __restrict__ qkv, const u16* __restrict__ colpart,
    const float* __restrict__ mH, const float* __restrict__ sH,
    const float* __restrict__ x, const float* __restrict__ y,
    const float* __restrict__ gamma_p, float* __restrict__ out)
{
    __shared__ __align__(16) float q_s[8*128];   // [o][w]
    __shared__ __align__(16) float k_sw[8*128];  // [u][o ^ ((u>>3)&7)]
    __shared__ __align__(16) u32  v2_s[64*67];   // [c][up]
    __shared__ __align__(16) u32  p2_s[128*66];  // [w][up ^ 2(w>>2&3)]
    __shared__ float fc_s[128], fr_s[128];

    int t = threadIdx.x;
    int b = blockIdx.x >> 7, h = blockIdx.x & 127;
    const u32* src = (const u32*)(qkv + (size_t)b*NCH*HW + h*128);

    #pragma unroll
    for (int r=0;r<2;r++){
        int idx = t + r*512;
        int ch = idx >> 6, wp = idx & 63;
        u32 pk = src[ch*8192 + wp];
        int u0 = wp*2;
        if (ch < 8){
            *(float2*)&q_s[ch*128 + u0] = make_float2(b2f_lo(pk), b2f_hi(pk));
        } else {
            int o = ch - 8;
            k_sw[u0*8     + (o ^ ((u0>>3)&7))]     = b2f_lo(pk);
            k_sw[(u0+1)*8 + (o ^ (((u0+1)>>3)&7))] = b2f_hi(pk);
        }
    }
    #pragma unroll
    for (int r=0;r<8;r++){
        int idx = t + r*512;
        int c = idx >> 6, up = idx & 63;
        v2_s[c*67 + up] = src[(16+c)*8192 + up];
    }
    __syncthreads();

    // ---- E over (w, u)
    int tr = t >> 4, tc = t & 15;
    int w0 = tr*4, u0 = tc*8;
    float e[4][8];
    #pragma unroll
    for (int i=0;i<4;i++)
        #pragma unroll
        for (int j=0;j<8;j++) e[i][j] = 0.f;

    #pragma unroll
    for (int o=0;o<8;o++){
        float qv[4], kv[8];
        #pragma unroll
        for (int i=0;i<4;i++) qv[i] = q_s[o*128 + w0 + i];
        int kb = o ^ (tc & 7);
        #pragma unroll
        for (int j=0;j<8;j++) kv[j] = k_sw[(u0+j)*8 + kb];
        #pragma unroll
        for (int i=0;i<4;i++)
            #pragma unroll
            for (int j=0;j<8;j++) e[i][j] += qv[i]*kv[j];
    }
    // no mask in row direction
    int f  = 2*(tr & 3);
    int Bb = (4*tc) ^ (f & 4);
    int pixbase = b*HW + h*128;
    #pragma unroll
    for (int i=0;i<4;i++){
        int wp = w0 + i;
        float m = e[i][0];
        #pragma unroll
        for (int j=1;j<8;j++) m = fmaxf(m, e[i][j]);
        m = fmaxf(m, __shfl_xor(m,1));
        m = fmaxf(m, __shfl_xor(m,2));
        m = fmaxf(m, __shfl_xor(m,4));
        m = fmaxf(m, __shfl_xor(m,8));
        float mh = mH[pixbase + wp];
        float sh = sH[pixbase + wp];
        float mg = fmaxf(m, mh);
        float s = 0.f;
        #pragma unroll
        for (int j=0;j<8;j++){ float pp = __expf(e[i][j]-mg); e[i][j]=pp; s += pp; }
        s += __shfl_xor(s,1);
        s += __shfl_xor(s,2);
        s += __shfl_xor(s,4);
        s += __shfl_xor(s,8);
        if (tc == 0){
            float ef = __expf(mh - mg);
            float stot = sh*ef + s;
            fc_s[wp] = ef/stot;
            fr_s[wp] = 1.0f/stot;
        }
        u32 pk0 = (u32)f2b(e[i][0]) | ((u32)f2b(e[i][1])<<16);
        u32 pk1 = (u32)f2b(e[i][2]) | ((u32)f2b(e[i][3])<<16);
        u32 pk2 = (u32)f2b(e[i][4]) | ((u32)f2b(e[i][5])<<16);
        u32 pk3 = (u32)f2b(e[i][6]) | ((u32)f2b(e[i][7])<<16);
        bool sw = (f & 2) != 0;
        uint2 loPair = sw ? make_uint2(pk2, pk3) : make_uint2(pk0, pk1);
        uint2 hiPair = sw ? make_uint2(pk0, pk1) : make_uint2(pk2, pk3);
        *(uint2*)&p2_s[wp*66 + Bb]     = loPair;
        *(uint2*)&p2_s[wp*66 + Bb + 2] = hiPair;
    }
    __syncthreads();

    // ---- PV: rowpart[c][w] over u, per-thread [4c][4w]
    int ci = t & 15, wq = t >> 4;
    int c0 = 4*ci, ww0 = 4*wq;
    int fv = 2*(wq & 3);
    float acc[4][4];
    #pragma unroll
    for (int k=0;k<4;k++)
        #pragma unroll
        for (int i=0;i<4;i++) acc[k][i] = 0.f;

    #pragma unroll 8
    for (int up=0; up<64; up++){
        int upp = up ^ fv;
        u32 pA = p2_s[(ww0+0)*66 + upp];
        u32 pB = p2_s[(ww0+1)*66 + upp];
        u32 pC = p2_s[(ww0+2)*66 + upp];
        u32 pD = p2_s[(ww0+3)*66 + upp];
        float pl[4] = {b2f_lo(pA), b2f_lo(pB), b2f_lo(pC), b2f_lo(pD)};
        float ph[4] = {b2f_hi(pA), b2f_hi(pB), b2f_hi(pC), b2f_hi(pD)};
        #pragma unroll
        for (int k=0;k<4;k++){
            u32 vv = v2_s[(c0+k)*67 + up];
            float vl = b2f_lo(vv), vh = b2f_hi(vv);
            #pragma unroll
            for (int i=0;i<4;i++) acc[k][i] += vl*pl[i] + vh*ph[i];
        }
    }
    // ---- combine + epilogue
    float gm = gamma_p[0];
    float fcv[4], frv[4];
    #pragma unroll
    for (int i=0;i<4;i++){ fcv[i] = fc_s[ww0+i]; frv[i] = fr_s[ww0+i]; }
    #pragma unroll
    for (int k=0;k<4;k++){
        size_t off = ((size_t)(b*64 + c0 + k)*128 + h)*128 + ww0;
        uint2 cpv = *(const uint2*)&colpart[off];
        float cp[4] = {b2f_lo(cpv.x), b2f_hi(cpv.x), b2f_lo(cpv.y), b2f_hi(cpv.y)};
        float4 xv = *(const float4*)&x[off];
        float4 yv = *(const float4*)&y[off];
        float4 o4;
        o4.x = gm*(cp[0]*fcv[0] + acc[k][0]*frv[0]) + xv.x + yv.x;
        o4.y = gm*(cp[1]*fcv[1] + acc[k][1]*frv[1]) + xv.y + yv.y;
        o4.z = gm*(cp[2]*fcv[2] + acc[k][2]*frv[2]) + xv.z + yv.z;
        o4.w = gm*(cp[3]*fcv[3] + acc[k][3]*frv[3]) + xv.w + yv.w;
        *(float4*)&out[off] = o4;
    }
}

// ----------------------------------------------------------------
extern "C" void kernel_launch(void* const* d_in, const int* in_sizes, int n_in,
                              void* d_out, int out_size, void* d_ws, size_t ws_size,
                              hipStream_t stream)
{
    (void)in_sizes; (void)n_in; (void)out_size; (void)ws_size;
    const float* x  = (const float*)d_in[0];
    const float* y  = (const float*)d_in[1];
    const float* qw = (const float*)d_in[2];
    const float* qb = (const float*)d_in[3];
    const float* kw = (const float*)d_in[4];
    const float* kb = (const float*)d_in[5];
    const float* vw = (const float*)d_in[6];
    const float* vb = (const float*)d_in[7];
    const float* gm = (const float*)d_in[8];
    float* out = (float*)d_out;

    char* ws = (char*)d_ws;
    u16* qkv   = (u16*)(ws);                      // 41,943,040 B
    u16* qkvT  = (u16*)(ws + 41943040ull);        // 41,943,040 B
    u16* colT  = (u16*)(ws + 83886080ull);        // 33,554,432 B
    u16* colpart = qkvT;                          // alias: qkvT dead after k_col
    float* mH  = (float*)(ws + 117440512ull);     // 1,048,576 B
    float* sH  = (float*)(ws + 118489088ull);     // 1,048,576 B

    k_qkv<<<1024, 256, 0, stream>>>(x, y, qw, qb, kw, kb, vw, vb, qkv);
    k_tr <<<5120, 256, 0, stream>>>(qkv, qkvT);          // 1280 planes
    k_col<<<2048, 512, 0, stream>>>(qkvT, colT, mH, sH);
    k_tr <<<4096, 256, 0, stream>>>(colT, colpart);      // 1024 planes
    k_row<<<2048, 512, 0, stream>>>(qkv, colpart, mH, sH, x, y, gm, out);
}

// Round 3
// 309.781 us; speedup vs baseline: 2.7355x; 1.2484x over previous
//
#include <hip/hip_runtime.h>

#define NCH 80
#define HW 16384

typedef unsigned short u16;
typedef unsigned int u32;
typedef short s16x8 __attribute__((ext_vector_type(8)));
typedef float f32x4 __attribute__((ext_vector_type(4)));

__device__ __forceinline__ float b2f_lo(u32 pk){ union{u32 u; float f;} c; c.u = pk<<16; return c.f; }
__device__ __forceinline__ float b2f_hi(u32 pk){ union{u32 u; float f;} c; c.u = pk & 0xffff0000u; return c.f; }
__device__ __forceinline__ float b2f(u16 v){ union{u32 u; float f;} c; c.u = ((u32)v)<<16; return c.f; }
__device__ __forceinline__ u16 f2b(float f){
    union{u32 u; float f;} c; c.f = f;
    return (u16)((c.u + 0x7fff + ((c.u>>16)&1))>>16);
}
// hardware bf16 convert (RNE) — lets compiler use v_cvt_pk_bf16_f32
__device__ __forceinline__ u16 f2b_hw(float f){
    union{ __bf16 h; u16 s; } c; c.h = (__bf16)f; return c.s;
}
#define NEG_INF (-__builtin_inff())

// ---------------------------------------------------------------- P0: weight pack -> bf16
// wbf[80][128] over cin = concat(x,y); bias80[80]
__global__ __launch_bounds__(256) void k_wcvt(
    const float* __restrict__ qw, const float* __restrict__ qb,
    const float* __restrict__ kw, const float* __restrict__ kb,
    const float* __restrict__ vw, const float* __restrict__ vb,
    u16* __restrict__ wbf, float* __restrict__ bias80)
{
    int i = blockIdx.x*256 + threadIdx.x;     // 0..10239
    int ch = i >> 7, cin = i & 127;
    float v;
    if (ch < 8)       v = (cin < 64) ? qw[ch*64 + cin] : 0.f;
    else if (ch < 16) v = (cin >= 64) ? kw[(ch-8)*64 + (cin-64)] : 0.f;
    else              v = vw[(ch-16)*128 + cin];
    wbf[i] = f2b_hw(v);
    if (i < 80){
        bias80[i] = (i<8) ? qb[i] : (i<16) ? kb[i-8] : vb[i-16];
    }
}

// ---------------------------------------------------------------- P1: qkv via MFMA
// grid: 4096 blocks x 256 thr (4 waves). Wave owns 16 pixels (M) x 80 ch (N) x K=128.
__global__ __launch_bounds__(256) void k_qkv_mfma(
    const float* __restrict__ x, const float* __restrict__ y,
    const u16* __restrict__ wbf, const float* __restrict__ bias80,
    u16* __restrict__ qkv)
{
    int t = threadIdx.x;
    int wv = t >> 6, l = t & 63;
    int lm = l & 15, q = l >> 4;
    int p0 = blockIdx.x * 64 + wv * 16;       // global pixel base for this wave
    int b = p0 >> 14, rem = p0 & 16383;

    // ---- A fragments: A[m=pixel][k=cin], lane: m=lm, k=(q*8+j) within K-step
    const float* xb = x + (size_t)b*64*HW + rem + lm;
    const float* yb = y + (size_t)b*64*HW + rem + lm;
    s16x8 af[4];
    #pragma unroll
    for (int ks=0; ks<4; ks++){
        const float* src = (ks < 2) ? xb : yb;
        int cin0 = (ks & 1)*32 + q*8;
        #pragma unroll
        for (int j=0;j<8;j++){
            float v = src[(size_t)(cin0 + j)*HW];
            af[ks][j] = (short)f2b_hw(v);
        }
    }

    // ---- B fragments from wbf (L2-resident), 5 N-tiles x 4 K-steps; MFMA
    f32x4 acc[5];
    #pragma unroll
    for (int mt=0; mt<5; mt++) acc[mt] = (f32x4){0.f,0.f,0.f,0.f};

    #pragma unroll
    for (int mt=0; mt<5; mt++){
        int ch = mt*16 + lm;
        const u16* wrow = wbf + ch*128 + q*8;
        #pragma unroll
        for (int ks=0; ks<4; ks++){
            s16x8 bfrag = *(const s16x8*)(wrow + ks*32);
            acc[mt] = __builtin_amdgcn_mfma_f32_16x16x32_bf16(af[ks], bfrag, acc[mt], 0, 0, 0);
        }
    }

    // ---- epilogue: +bias, pack 4 consecutive pixels (regs) per lane, 8B store
    #pragma unroll
    for (int mt=0; mt<5; mt++){
        int ch = mt*16 + lm;
        float bs = bias80[ch];
        u32 lo = (u32)f2b_hw(acc[mt][0]+bs) | ((u32)f2b_hw(acc[mt][1]+bs)<<16);
        u32 hi = (u32)f2b_hw(acc[mt][2]+bs) | ((u32)f2b_hw(acc[mt][3]+bs)<<16);
        *(uint2*)&qkv[(size_t)(b*NCH + ch)*HW + rem + q*4] = make_uint2(lo, hi);
    }
}

// ------------------------------------------------ 128x128 bf16 plane transpose (unchanged)
__global__ __launch_bounds__(256) void k_tr(const u16* __restrict__ src, u16* __restrict__ dst)
{
    __shared__ u16 tile[64][65];
    int blk = blockIdx.x;
    int plane = blk >> 2, tq = blk & 3;
    int r0 = (tq >> 1) * 64, c0 = (tq & 1) * 64;
    const u16* s = src + (size_t)plane * HW;
    u16* d = dst + (size_t)plane * HW;
    int col = threadIdx.x & 63, rr = threadIdx.x >> 6;
    #pragma unroll
    for (int k=0;k<16;k++){
        int r = k*4 + rr;
        tile[r][col] = s[(r0+r)*128 + c0 + col];
    }
    __syncthreads();
    #pragma unroll
    for (int k=0;k<16;k++){
        int r = k*4 + rr;
        d[(c0+r)*128 + r0 + col] = tile[col][r];
    }
}

// ---------------------------------------------------------------- P2: column pass (unchanged from R2)
__global__ __launch_bounds__(512, 4) void k_col(
    const u16* __restrict__ qkvT, u16* __restrict__ colT,
    float* __restrict__ mH, float* __restrict__ sH)
{
    __shared__ __align__(16) float q_s[8*128];   // [o][h]
    __shared__ __align__(16) float k_sw[8*128];  // [g][o ^ ((g>>3)&7)]
    __shared__ __align__(16) u32  v2_s[64*67];   // [c][gp] bf16-pair
    __shared__ __align__(16) u32  p2_s[128*66];  // [h][gp ^ 2(h>>2&3)]

    int t = threadIdx.x;
    int b = blockIdx.x >> 7, w = blockIdx.x & 127;
    const u32* src = (const u32*)(qkvT + (size_t)b*NCH*HW + w*128);

    #pragma unroll
    for (int r=0;r<2;r++){
        int idx = t + r*512;
        int ch = idx >> 6, hp = idx & 63;
        u32 pk = src[ch*8192 + hp];
        int g0 = hp*2;
        if (ch < 8){
            *(float2*)&q_s[ch*128 + g0] = make_float2(b2f_lo(pk), b2f_hi(pk));
        } else {
            int o = ch - 8;
            k_sw[g0*8     + (o ^ ((g0>>3)&7))]     = b2f_lo(pk);
            k_sw[(g0+1)*8 + (o ^ (((g0+1)>>3)&7))] = b2f_hi(pk);
        }
    }
    #pragma unroll
    for (int r=0;r<8;r++){
        int idx = t + r*512;
        int c = idx >> 6, gp = idx & 63;
        v2_s[c*67 + gp] = src[(16+c)*8192 + gp];
    }
    __syncthreads();

    int tr = t >> 4, tc = t & 15;
    int h0 = tr*4, g0 = tc*8;
    float e[4][8];
    #pragma unroll
    for (int i=0;i<4;i++)
        #pragma unroll
        for (int j=0;j<8;j++) e[i][j] = 0.f;

    #pragma unroll
    for (int o=0;o<8;o++){
        float qv[4], kv[8];
        #pragma unroll
        for (int i=0;i<4;i++) qv[i] = q_s[o*128 + h0 + i];
        int kb = o ^ (tc & 7);
        #pragma unroll
        for (int j=0;j<8;j++) kv[j] = k_sw[(g0+j)*8 + kb];
        #pragma unroll
        for (int i=0;i<4;i++)
            #pragma unroll
            for (int j=0;j<8;j++) e[i][j] += qv[i]*kv[j];
    }
    #pragma unroll
    for (int i=0;i<4;i++){
        int h = h0 + i;
        if ((h>>3) == tc) e[i][h&7] = NEG_INF;
    }
    int f  = 2*(tr & 3);
    int Bb = (4*tc) ^ (f & 4);
    #pragma unroll
    for (int i=0;i<4;i++){
        int h = h0 + i;
        float m = e[i][0];
        #pragma unroll
        for (int j=1;j<8;j++) m = fmaxf(m, e[i][j]);
        m = fmaxf(m, __shfl_xor(m,1));
        m = fmaxf(m, __shfl_xor(m,2));
        m = fmaxf(m, __shfl_xor(m,4));
        m = fmaxf(m, __shfl_xor(m,8));
        float s = 0.f;
        #pragma unroll
        for (int j=0;j<8;j++){ float pp = __expf(e[i][j]-m); e[i][j]=pp; s += pp; }
        s += __shfl_xor(s,1);
        s += __shfl_xor(s,2);
        s += __shfl_xor(s,4);
        s += __shfl_xor(s,8);
        if (tc == 0){
            mH[b*HW + h*128 + w] = m;
            sH[b*HW + h*128 + w] = s;
        }
        u32 pk0 = (u32)f2b(e[i][0]) | ((u32)f2b(e[i][1])<<16);
        u32 pk1 = (u32)f2b(e[i][2]) | ((u32)f2b(e[i][3])<<16);
        u32 pk2 = (u32)f2b(e[i][4]) | ((u32)f2b(e[i][5])<<16);
        u32 pk3 = (u32)f2b(e[i][6]) | ((u32)f2b(e[i][7])<<16);
        bool sw = (f & 2) != 0;
        uint2 loPair = sw ? make_uint2(pk2, pk3) : make_uint2(pk0, pk1);
        uint2 hiPair = sw ? make_uint2(pk0, pk1) : make_uint2(pk2, pk3);
        *(uint2*)&p2_s[h*66 + Bb]     = loPair;
        *(uint2*)&p2_s[h*66 + Bb + 2] = hiPair;
    }
    __syncthreads();

    int ci = t & 15, hq = t >> 4;
    int c0 = 4*ci, hh0 = 4*hq;
    int fv = 2*(hq & 3);
    float acc[4][4];
    #pragma unroll
    for (int k=0;k<4;k++)
        #pragma unroll
        for (int i=0;i<4;i++) acc[k][i] = 0.f;

    #pragma unroll 8
    for (int gp=0; gp<64; gp++){
        int gpp = gp ^ fv;
        u32 pA = p2_s[(hh0+0)*66 + gpp];
        u32 pB = p2_s[(hh0+1)*66 + gpp];
        u32 pC = p2_s[(hh0+2)*66 + gpp];
        u32 pD = p2_s[(hh0+3)*66 + gpp];
        float pl[4] = {b2f_lo(pA), b2f_lo(pB), b2f_lo(pC), b2f_lo(pD)};
        float ph[4] = {b2f_hi(pA), b2f_hi(pB), b2f_hi(pC), b2f_hi(pD)};
        #pragma unroll
        for (int k=0;k<4;k++){
            u32 vv = v2_s[(c0+k)*67 + gp];
            float vl = b2f_lo(vv), vh = b2f_hi(vv);
            #pragma unroll
            for (int i=0;i<4;i++) acc[k][i] += vl*pl[i] + vh*ph[i];
        }
    }
    #pragma unroll
    for (int k=0;k<4;k++){
        uint2 st;
        st.x = (u32)f2b(acc[k][0]) | ((u32)f2b(acc[k][1])<<16);
        st.y = (u32)f2b(acc[k][2]) | ((u32)f2b(acc[k][3])<<16);
        *(uint2*)&colT[((size_t)(b*64 + c0 + k)*128 + w)*128 + hh0] = st;
    }
}

// ---------------------------------------------------------------- P3: row pass + combine (unchanged from R2)
__global__ __launch_bounds__(512, 4) void k_row(
    const u16* __restrict__ qkv, const u16* __restrict__ colpart,
    const float* __restrict__ mH, const float* __restrict__ sH,
    const float* __restrict__ x, const float* __restrict__ y,
    const float* __restrict__ gamma_p, float* __restrict__ out)
{
    __shared__ __align__(16) float q_s[8*128];
    __shared__ __align__(16) float k_sw[8*128];
    __shared__ __align__(16) u32  v2_s[64*67];
    __shared__ __align__(16) u32  p2_s[128*66];
    __shared__ float fc_s[128], fr_s[128];

    int t = threadIdx.x;
    int b = blockIdx.x >> 7, h = blockIdx.x & 127;
    const u32* src = (const u32*)(qkv + (size_t)b*NCH*HW + h*128);

    #pragma unroll
    for (int r=0;r<2;r++){
        int idx = t + r*512;
        int ch = idx >> 6, wp = idx & 63;
        u32 pk = src[ch*8192 + wp];
        int u0 = wp*2;
        if (ch < 8){
            *(float2*)&q_s[ch*128 + u0] = make_float2(b2f_lo(pk), b2f_hi(pk));
        } else {
            int o = ch - 8;
            k_sw[u0*8     + (o ^ ((u0>>3)&7))]     = b2f_lo(pk);
            k_sw[(u0+1)*8 + (o ^ (((u0+1)>>3)&7))] = b2f_hi(pk);
        }
    }
    #pragma unroll
    for (int r=0;r<8;r++){
        int idx = t + r*512;
        int c = idx >> 6, up = idx & 63;
        v2_s[c*67 + up] = src[(16+c)*8192 + up];
    }
    __syncthreads();

    int tr = t >> 4, tc = t & 15;
    int w0 = tr*4, u0 = tc*8;
    float e[4][8];
    #pragma unroll
    for (int i=0;i<4;i++)
        #pragma unroll
        for (int j=0;j<8;j++) e[i][j] = 0.f;

    #pragma unroll
    for (int o=0;o<8;o++){
        float qv[4], kv[8];
        #pragma unroll
        for (int i=0;i<4;i++) qv[i] = q_s[o*128 + w0 + i];
        int kb = o ^ (tc & 7);
        #pragma unroll
        for (int j=0;j<8;j++) kv[j] = k_sw[(u0+j)*8 + kb];
        #pragma unroll
        for (int i=0;i<4;i++)
            #pragma unroll
            for (int j=0;j<8;j++) e[i][j] += qv[i]*kv[j];
    }
    int f  = 2*(tr & 3);
    int Bb = (4*tc) ^ (f & 4);
    int pixbase = b*HW + h*128;
    #pragma unroll
    for (int i=0;i<4;i++){
        int wp = w0 + i;
        float m = e[i][0];
        #pragma unroll
        for (int j=1;j<8;j++) m = fmaxf(m, e[i][j]);
        m = fmaxf(m, __shfl_xor(m,1));
        m = fmaxf(m, __shfl_xor(m,2));
        m = fmaxf(m, __shfl_xor(m,4));
        m = fmaxf(m, __shfl_xor(m,8));
        float mh = mH[pixbase + wp];
        float sh = sH[pixbase + wp];
        float mg = fmaxf(m, mh);
        float s = 0.f;
        #pragma unroll
        for (int j=0;j<8;j++){ float pp = __expf(e[i][j]-mg); e[i][j]=pp; s += pp; }
        s += __shfl_xor(s,1);
        s += __shfl_xor(s,2);
        s += __shfl_xor(s,4);
        s += __shfl_xor(s,8);
        if (tc == 0){
            float ef = __expf(mh - mg);
            float stot = sh*ef + s;
            fc_s[wp] = ef/stot;
            fr_s[wp] = 1.0f/stot;
        }
        u32 pk0 = (u32)f2b(e[i][0]) | ((u32)f2b(e[i][1])<<16);
        u32 pk1 = (u32)f2b(e[i][2]) | ((u32)f2b(e[i][3])<<16);
        u32 pk2 = (u32)f2b(e[i][4]) | ((u32)f2b(e[i][5])<<16);
        u32 pk3 = (u32)f2b(e[i][6]) | ((u32)f2b(e[i][7])<<16);
        bool sw = (f & 2) != 0;
        uint2 loPair = sw ? make_uint2(pk2, pk3) : make_uint2(pk0, pk1);
        uint2 hiPair = sw ? make_uint2(pk0, pk1) : make_uint2(pk2, pk3);
        *(uint2*)&p2_s[wp*66 + Bb]     = loPair;
        *(uint2*)&p2_s[wp*66 + Bb + 2] = hiPair;
    }
    __syncthreads();

    int ci = t & 15, wq = t >> 4;
    int c0 = 4*ci, ww0 = 4*wq;
    int fv = 2*(wq & 3);
    float acc[4][4];
    #pragma unroll
    for (int k=0;k<4;k++)
        #pragma unroll
        for (int i=0;i<4;i++) acc[k][i] = 0.f;

    #pragma unroll 8
    for (int up=0; up<64; up++){
        int upp = up ^ fv;
        u32 pA = p2_s[(ww0+0)*66 + upp];
        u32 pB = p2_s[(ww0+1)*66 + upp];
        u32 pC = p2_s[(ww0+2)*66 + upp];
        u32 pD = p2_s[(ww0+3)*66 + upp];
        float pl[4] = {b2f_lo(pA), b2f_lo(pB), b2f_lo(pC), b2f_lo(pD)};
        float ph[4] = {b2f_hi(pA), b2f_hi(pB), b2f_hi(pC), b2f_hi(pD)};
        #pragma unroll
        for (int k=0;k<4;k++){
            u32 vv = v2_s[(c0+k)*67 + up];
            float vl = b2f_lo(vv), vh = b2f_hi(vv);
            #pragma unroll
            for (int i=0;i<4;i++) acc[k][i] += vl*pl[i] + vh*ph[i];
        }
    }
    float gm = gamma_p[0];
    float fcv[4], frv[4];
    #pragma unroll
    for (int i=0;i<4;i++){ fcv[i] = fc_s[ww0+i]; frv[i] = fr_s[ww0+i]; }
    #pragma unroll
    for (int k=0;k<4;k++){
        size_t off = ((size_t)(b*64 + c0 + k)*128 + h)*128 + ww0;
        uint2 cpv = *(const uint2*)&colpart[off];
        float cp[4] = {b2f_lo(cpv.x), b2f_hi(cpv.x), b2f_lo(cpv.y), b2f_hi(cpv.y)};
        float4 xv = *(const float4*)&x[off];
        float4 yv = *(const float4*)&y[off];
        float4 o4;
        o4.x = gm*(cp[0]*fcv[0] + acc[k][0]*frv[0]) + xv.x + yv.x;
        o4.y = gm*(cp[1]*fcv[1] + acc[k][1]*frv[1]) + xv.y + yv.y;
        o4.z = gm*(cp[2]*fcv[2] + acc[k][2]*frv[2]) + xv.z + yv.z;
        o4.w = gm*(cp[3]*fcv[3] + acc[k][3]*frv[3]) + xv.w + yv.w;
        *(float4*)&out[off] = o4;
    }
}

// ----------------------------------------------------------------
extern "C" void kernel_launch(void* const* d_in, const int* in_sizes, int n_in,
                              void* d_out, int out_size, void* d_ws, size_t ws_size,
                              hipStream_t stream)
{
    (void)in_sizes; (void)n_in; (void)out_size; (void)ws_size;
    const float* x  = (const float*)d_in[0];
    const float* y  = (const float*)d_in[1];
    const float* qw = (const float*)d_in[2];
    const float* qb = (const float*)d_in[3];
    const float* kw = (const float*)d_in[4];
    const float* kb = (const float*)d_in[5];
    const float* vw = (const float*)d_in[6];
    const float* vb = (const float*)d_in[7];
    const float* gm = (const float*)d_in[8];
    float* out = (float*)d_out;

    char* ws = (char*)d_ws;
    u16* qkv     = (u16*)(ws);                    // 41,943,040 B
    u16* qkvT    = (u16*)(ws + 41943040ull);      // 41,943,040 B
    u16* colT    = (u16*)(ws + 83886080ull);      // 33,554,432 B
    u16* colpart = qkvT;                          // alias: qkvT dead after k_col
    float* mH    = (float*)(ws + 117440512ull);   // 1,048,576 B
    float* sH    = (float*)(ws + 118489088ull);   // 1,048,576 B
    u16* wbf     = (u16*)(ws + 119537664ull);     // 20,480 B
    float* bias80= (float*)(ws + 119558144ull);   // 320 B

    k_wcvt<<<40, 256, 0, stream>>>(qw, qb, kw, kb, vw, vb, wbf, bias80);
    k_qkv_mfma<<<4096, 256, 0, stream>>>(x, y, wbf, bias80, qkv);
    k_tr <<<5120, 256, 0, stream>>>(qkv, qkvT);          // 1280 planes
    k_col<<<2048, 512, 0, stream>>>(qkvT, colT, mH, sH);
    k_tr <<<4096, 256, 0, stream>>>(colT, colpart);      // 1024 planes
    k_row<<<2048, 512, 0, stream>>>(qkv, colpart, mH, sH, x, y, gm, out);
}

// Round 4
// 193.543 us; speedup vs baseline: 4.3783x; 1.6006x over previous
//
#include <hip/hip_runtime.h>

#define NCH 80
#define HW 16384

typedef unsigned short u16;
typedef unsigned int u32;
typedef short s16x8 __attribute__((ext_vector_type(8)));
typedef float f32x4 __attribute__((ext_vector_type(4)));

__device__ __forceinline__ float b2f_lo(u32 pk){ union{u32 u; float f;} c; c.u = pk<<16; return c.f; }
__device__ __forceinline__ float b2f_hi(u32 pk){ union{u32 u; float f;} c; c.u = pk & 0xffff0000u; return c.f; }
__device__ __forceinline__ float b2f(u16 v){ union{u32 u; float f;} c; c.u = ((u32)v)<<16; return c.f; }
__device__ __forceinline__ u16 f2b_hw(float f){
    union{ __bf16 h; u16 s; } c; c.h = (__bf16)f; return c.s;
}
__device__ __forceinline__ u32 pk2(float a, float b){
    return (u32)f2b_hw(a) | ((u32)f2b_hw(b)<<16);
}
#define NEG_INF (-__builtin_inff())

// ---------------------------------------------------------------- P0: weight pack -> bf16
__global__ __launch_bounds__(256) void k_wcvt(
    const float* __restrict__ qw, const float* __restrict__ qb,
    const float* __restrict__ kw, const float* __restrict__ kb,
    const float* __restrict__ vw, const float* __restrict__ vb,
    u16* __restrict__ wbf, float* __restrict__ bias80)
{
    int i = blockIdx.x*256 + threadIdx.x;     // 0..10239
    int ch = i >> 7, cin = i & 127;
    float v;
    if (ch < 8)       v = (cin < 64) ? qw[ch*64 + cin] : 0.f;
    else if (ch < 16) v = (cin >= 64) ? kw[(ch-8)*64 + (cin-64)] : 0.f;
    else              v = vw[(ch-16)*128 + cin];
    wbf[i] = f2b_hw(v);
    if (i < 80){
        bias80[i] = (i<8) ? qb[i] : (i<16) ? kb[i-8] : vb[i-16];
    }
}

// ---------------------------------------------------------------- P1: qkv via MFMA (+xy emit)
__global__ __launch_bounds__(256) void k_qkv_mfma(
    const float* __restrict__ x, const float* __restrict__ y,
    const u16* __restrict__ wbf, const float* __restrict__ bias80,
    u16* __restrict__ qkv, u16* __restrict__ xy)
{
    int t = threadIdx.x;
    int wv = t >> 6, l = t & 63;
    int lm = l & 15, q = l >> 4;
    int p0 = blockIdx.x * 64 + wv * 16;
    int b = p0 >> 14, rem = p0 & 16383;

    const float* xb = x + (size_t)b*64*HW + rem + lm;
    const float* yb = y + (size_t)b*64*HW + rem + lm;
    float xf[4][8];
    #pragma unroll
    for (int ks=0; ks<4; ks++){
        const float* srcp = (ks < 2) ? xb : yb;
        int cin0 = (ks & 1)*32 + q*8;
        #pragma unroll
        for (int j=0;j<8;j++) xf[ks][j] = srcp[(size_t)(cin0 + j)*HW];
    }
    s16x8 af[4];
    #pragma unroll
    for (int ks=0; ks<4; ks++)
        #pragma unroll
        for (int j=0;j<8;j++) af[ks][j] = (short)f2b_hw(xf[ks][j]);

    if (xy){
        #pragma unroll
        for (int half=0; half<2; half++)
            #pragma unroll
            for (int j=0;j<8;j++){
                int c = half*32 + q*8 + j;
                xy[(size_t)(b*64+c)*HW + rem + lm] = f2b_hw(xf[half][j] + xf[half+2][j]);
            }
    }

    f32x4 acc[5];
    #pragma unroll
    for (int mt=0; mt<5; mt++) acc[mt] = (f32x4){0.f,0.f,0.f,0.f};

    #pragma unroll
    for (int mt=0; mt<5; mt++){
        int ch = mt*16 + lm;
        const u16* wrow = wbf + ch*128 + q*8;
        #pragma unroll
        for (int ks=0; ks<4; ks++){
            s16x8 bfrag = *(const s16x8*)(wrow + ks*32);
            acc[mt] = __builtin_amdgcn_mfma_f32_16x16x32_bf16(af[ks], bfrag, acc[mt], 0, 0, 0);
        }
    }

    #pragma unroll
    for (int mt=0; mt<5; mt++){
        int ch = mt*16 + lm;
        float bs = bias80[ch];
        u32 lo = pk2(acc[mt][0]+bs, acc[mt][1]+bs);
        u32 hi = pk2(acc[mt][2]+bs, acc[mt][3]+bs);
        *(uint2*)&qkv[(size_t)(b*NCH + ch)*HW + rem + q*4] = make_uint2(lo, hi);
    }
}

// ------------------------------------------------ 128x128 bf16 plane transpose (unchanged)
__global__ __launch_bounds__(256) void k_tr(const u16* __restrict__ src, u16* __restrict__ dst)
{
    __shared__ u16 tile[64][65];
    int blk = blockIdx.x;
    int plane = blk >> 2, tq = blk & 3;
    int r0 = (tq >> 1) * 64, c0 = (tq & 1) * 64;
    const u16* s = src + (size_t)plane * HW;
    u16* d = dst + (size_t)plane * HW;
    int col = threadIdx.x & 63, rr = threadIdx.x >> 6;
    #pragma unroll
    for (int k=0;k<16;k++){
        int r = k*4 + rr;
        tile[r][col] = s[(r0+r)*128 + c0 + col];
    }
    __syncthreads();
    #pragma unroll
    for (int k=0;k<16;k++){
        int r = k*4 + rr;
        d[(c0+r)*128 + r0 + col] = tile[col][r];
    }
}

// ---------------------------------------------------------------- P2: column pass v3 (MFMA PV)
// block = (b, w), 512 threads = 8 waves. qkvT layout: [(b*80+ch)][w][h]
__global__ __launch_bounds__(512, 4) void k_col(
    const u16* __restrict__ qkvT, u16* __restrict__ colT,
    float* __restrict__ mH, float* __restrict__ sH)
{
    __shared__ __align__(16) float q_s[8*128];    // [o][h]
    __shared__ __align__(16) float k_sw[8*128];   // [g][o^((g>>3)&7)]
    __shared__ __align__(16) u16  v_bf[64*128];   // [c][g], word ^ ((c&7)<<2)
    __shared__ __align__(16) u16  p_bf[128*128];  // [h][g], word ^ ((h&7)<<2)

    int t = threadIdx.x;
    int b = blockIdx.x >> 7, w = blockIdx.x & 127;
    const u32* src = (const u32*)(qkvT + (size_t)b*NCH*HW + w*128);
    u32* v32 = (u32*)v_bf;
    u32* p32 = (u32*)p_bf;

    // ---- staging
    #pragma unroll
    for (int r=0;r<2;r++){
        int idx = t + r*512;
        int ch = idx >> 6, hp = idx & 63;
        u32 pk = src[ch*8192 + hp];
        int g0 = hp*2;
        if (ch < 8){
            *(float2*)&q_s[ch*128 + g0] = make_float2(b2f_lo(pk), b2f_hi(pk));
        } else {
            int o = ch - 8;
            k_sw[g0*8     + (o ^ ((g0>>3)&7))]     = b2f_lo(pk);
            k_sw[(g0+1)*8 + (o ^ (((g0+1)>>3)&7))] = b2f_hi(pk);
        }
    }
    #pragma unroll
    for (int r=0;r<8;r++){
        int idx = t + r*512;
        int c = idx >> 6, gp = idx & 63;
        v32[(c*64 + gp) ^ ((c&7)<<2)] = src[(16+c)*8192 + gp];
    }
    __syncthreads();

    // ---- E = Q^T K : per-thread tile [4h][8g]
    int tr = t >> 4, tc = t & 15;
    int h0 = tr*4, g0 = tc*8;
    float e[4][8];
    #pragma unroll
    for (int i=0;i<4;i++)
        #pragma unroll
        for (int j=0;j<8;j++) e[i][j] = 0.f;

    #pragma unroll
    for (int o=0;o<8;o++){
        float qv[4], kv[8];
        #pragma unroll
        for (int i=0;i<4;i++) qv[i] = q_s[o*128 + h0 + i];
        int kb = o ^ (tc & 7);
        #pragma unroll
        for (int j=0;j<8;j++) kv[j] = k_sw[(g0+j)*8 + kb];
        #pragma unroll
        for (int i=0;i<4;i++)
            #pragma unroll
            for (int j=0;j<8;j++) e[i][j] += qv[i]*kv[j];
    }
    #pragma unroll
    for (int i=0;i<4;i++){
        int h = h0 + i;
        if ((h>>3) == tc) e[i][h&7] = NEG_INF;
    }
    // ---- softmax stats (column-local), pack p -> swizzled bf16 LDS
    #pragma unroll
    for (int i=0;i<4;i++){
        int h = h0 + i;
        float m = e[i][0];
        #pragma unroll
        for (int j=1;j<8;j++) m = fmaxf(m, e[i][j]);
        m = fmaxf(m, __shfl_xor(m,1));
        m = fmaxf(m, __shfl_xor(m,2));
        m = fmaxf(m, __shfl_xor(m,4));
        m = fmaxf(m, __shfl_xor(m,8));
        float s = 0.f;
        #pragma unroll
        for (int j=0;j<8;j++){ float pp = __expf(e[i][j]-m); e[i][j]=pp; s += pp; }
        s += __shfl_xor(s,1);
        s += __shfl_xor(s,2);
        s += __shfl_xor(s,4);
        s += __shfl_xor(s,8);
        if (tc == 0){
            mH[b*HW + h*128 + w] = m;
            sH[b*HW + h*128 + w] = s;
        }
        uint4 pw;
        pw.x = pk2(e[i][0], e[i][1]);
        pw.y = pk2(e[i][2], e[i][3]);
        pw.z = pk2(e[i][4], e[i][5]);
        pw.w = pk2(e[i][6], e[i][7]);
        *(uint4*)&p32[(h*64 + tc*4) ^ ((h&7)<<2)] = pw;
    }
    __syncthreads();

    // ---- PV via MFMA: D[m=h][n=c] = sum_g P[h][g] * V[c][g]
    int wv = t >> 6, l = t & 63;
    int lm = l & 15, lq = l >> 4;
    int mt = wv;                         // h-tile
    f32x4 acc[4];
    #pragma unroll
    for (int nt=0; nt<4; nt++) acc[nt] = (f32x4){0.f,0.f,0.f,0.f};

    #pragma unroll
    for (int ks=0; ks<4; ks++){
        int ri = mt*16 + lm;
        s16x8 a = *(const s16x8*)&p32[(ri*64 + ks*16 + lq*4) ^ ((ri&7)<<2)];
        #pragma unroll
        for (int nt=0; nt<4; nt++){
            int c = nt*16 + lm;
            s16x8 bf_ = *(const s16x8*)&v32[(c*64 + ks*16 + lq*4) ^ ((c&7)<<2)];
            acc[nt] = __builtin_amdgcn_mfma_f32_16x16x32_bf16(a, bf_, acc[nt], 0, 0, 0);
        }
    }
    // lane: c = nt*16+lm (col), h = mt*16 + lq*4 + reg (4 consecutive rows)
    #pragma unroll
    for (int nt=0; nt<4; nt++){
        int c = nt*16 + lm;
        int hh = mt*16 + lq*4;
        uint2 st;
        st.x = pk2(acc[nt][0], acc[nt][1]);
        st.y = pk2(acc[nt][2], acc[nt][3]);
        *(uint2*)&colT[((size_t)(b*64+c)*128 + w)*128 + hh] = st;
    }
}

// ---------------------------------------------------------------- P3: row pass + combine v3 (MFMA PV)
// block = (b, h), 512 threads. qkv natural layout.
__global__ __launch_bounds__(512, 4) void k_row(
    const u16* __restrict__ qkv, const u16* __restrict__ colpart,
    const float* __restrict__ mH, const float* __restrict__ sH,
    const float* __restrict__ x, const float* __restrict__ y,
    const u16* __restrict__ xy,
    const float* __restrict__ gamma_p, float* __restrict__ out)
{
    __shared__ __align__(16) float q_s[8*128];
    __shared__ __align__(16) float k_sw[8*128];
    __shared__ __align__(16) u16  v_bf[64*128];
    __shared__ __align__(16) u16  p_bf[128*128];
    __shared__ float fc_s[128], fr_s[128];

    int t = threadIdx.x;
    int b = blockIdx.x >> 7, h = blockIdx.x & 127;
    const u32* src = (const u32*)(qkv + (size_t)b*NCH*HW + h*128);
    u32* v32 = (u32*)v_bf;
    u32* p32 = (u32*)p_bf;

    #pragma unroll
    for (int r=0;r<2;r++){
        int idx = t + r*512;
        int ch = idx >> 6, wp = idx & 63;
        u32 pk = src[ch*8192 + wp];
        int u0 = wp*2;
        if (ch < 8){
            *(float2*)&q_s[ch*128 + u0] = make_float2(b2f_lo(pk), b2f_hi(pk));
        } else {
            int o = ch - 8;
            k_sw[u0*8     + (o ^ ((u0>>3)&7))]     = b2f_lo(pk);
            k_sw[(u0+1)*8 + (o ^ (((u0+1)>>3)&7))] = b2f_hi(pk);
        }
    }
    #pragma unroll
    for (int r=0;r<8;r++){
        int idx = t + r*512;
        int c = idx >> 6, up = idx & 63;
        v32[(c*64 + up) ^ ((c&7)<<2)] = src[(16+c)*8192 + up];
    }
    __syncthreads();

    int tr = t >> 4, tc = t & 15;
    int w0 = tr*4, u0 = tc*8;
    float e[4][8];
    #pragma unroll
    for (int i=0;i<4;i++)
        #pragma unroll
        for (int j=0;j<8;j++) e[i][j] = 0.f;

    #pragma unroll
    for (int o=0;o<8;o++){
        float qv[4], kv[8];
        #pragma unroll
        for (int i=0;i<4;i++) qv[i] = q_s[o*128 + w0 + i];
        int kb = o ^ (tc & 7);
        #pragma unroll
        for (int j=0;j<8;j++) kv[j] = k_sw[(u0+j)*8 + kb];
        #pragma unroll
        for (int i=0;i<4;i++)
            #pragma unroll
            for (int j=0;j<8;j++) e[i][j] += qv[i]*kv[j];
    }
    int pixbase = b*HW + h*128;
    #pragma unroll
    for (int i=0;i<4;i++){
        int wp = w0 + i;
        float m = e[i][0];
        #pragma unroll
        for (int j=1;j<8;j++) m = fmaxf(m, e[i][j]);
        m = fmaxf(m, __shfl_xor(m,1));
        m = fmaxf(m, __shfl_xor(m,2));
        m = fmaxf(m, __shfl_xor(m,4));
        m = fmaxf(m, __shfl_xor(m,8));
        float mh = mH[pixbase + wp];
        float sh = sH[pixbase + wp];
        float mg = fmaxf(m, mh);
        float s = 0.f;
        #pragma unroll
        for (int j=0;j<8;j++){ float pp = __expf(e[i][j]-mg); e[i][j]=pp; s += pp; }
        s += __shfl_xor(s,1);
        s += __shfl_xor(s,2);
        s += __shfl_xor(s,4);
        s += __shfl_xor(s,8);
        if (tc == 0){
            float ef = __expf(mh - mg);
            float stot = sh*ef + s;
            fc_s[wp] = ef/stot;
            fr_s[wp] = 1.0f/stot;
        }
        uint4 pw;
        pw.x = pk2(e[i][0], e[i][1]);
        pw.y = pk2(e[i][2], e[i][3]);
        pw.z = pk2(e[i][4], e[i][5]);
        pw.w = pk2(e[i][6], e[i][7]);
        *(uint4*)&p32[(wp*64 + tc*4) ^ ((wp&7)<<2)] = pw;
    }
    __syncthreads();

    // ---- PV via MFMA: D[m=w][n=c] = sum_u P[w][u] * V[c][u]
    int wv = t >> 6, l = t & 63;
    int lm = l & 15, lq = l >> 4;
    int mt = wv;
    f32x4 acc[4];
    #pragma unroll
    for (int nt=0; nt<4; nt++) acc[nt] = (f32x4){0.f,0.f,0.f,0.f};

    #pragma unroll
    for (int ks=0; ks<4; ks++){
        int ri = mt*16 + lm;
        s16x8 a = *(const s16x8*)&p32[(ri*64 + ks*16 + lq*4) ^ ((ri&7)<<2)];
        #pragma unroll
        for (int nt=0; nt<4; nt++){
            int c = nt*16 + lm;
            s16x8 bf_ = *(const s16x8*)&v32[(c*64 + ks*16 + lq*4) ^ ((c&7)<<2)];
            acc[nt] = __builtin_amdgcn_mfma_f32_16x16x32_bf16(a, bf_, acc[nt], 0, 0, 0);
        }
    }
    // ---- combine + epilogue: lane: c = nt*16+lm, w = mt*16 + lq*4 + reg
    float gm = gamma_p[0];
    int wq0 = mt*16 + lq*4;
    float fcv[4], frv[4];
    #pragma unroll
    for (int r2=0;r2<4;r2++){ fcv[r2] = fc_s[wq0+r2]; frv[r2] = fr_s[wq0+r2]; }

    #pragma unroll
    for (int nt=0; nt<4; nt++){
        int c = nt*16 + lm;
        size_t off = ((size_t)(b*64+c)*128 + h)*128 + wq0;
        uint2 cpv = *(const uint2*)&colpart[off];
        float cp[4] = {b2f_lo(cpv.x), b2f_hi(cpv.x), b2f_lo(cpv.y), b2f_hi(cpv.y)};
        float xs[4];
        if (xy){
            uint2 xv = *(const uint2*)&xy[off];
            xs[0]=b2f_lo(xv.x); xs[1]=b2f_hi(xv.x); xs[2]=b2f_lo(xv.y); xs[3]=b2f_hi(xv.y);
        } else {
            float4 x4 = *(const float4*)&x[off];
            float4 y4 = *(const float4*)&y[off];
            xs[0]=x4.x+y4.x; xs[1]=x4.y+y4.y; xs[2]=x4.z+y4.z; xs[3]=x4.w+y4.w;
        }
        float4 o4;
        o4.x = gm*(cp[0]*fcv[0] + acc[nt][0]*frv[0]) + xs[0];
        o4.y = gm*(cp[1]*fcv[1] + acc[nt][1]*frv[1]) + xs[1];
        o4.z = gm*(cp[2]*fcv[2] + acc[nt][2]*frv[2]) + xs[2];
        o4.w = gm*(cp[3]*fcv[3] + acc[nt][3]*frv[3]) + xs[3];
        *(float4*)&out[off] = o4;
    }
}

// ----------------------------------------------------------------
extern "C" void kernel_launch(void* const* d_in, const int* in_sizes, int n_in,
                              void* d_out, int out_size, void* d_ws, size_t ws_size,
                              hipStream_t stream)
{
    (void)in_sizes; (void)n_in; (void)out_size;
    const float* x  = (const float*)d_in[0];
    const float* y  = (const float*)d_in[1];
    const float* qw = (const float*)d_in[2];
    const float* qb = (const float*)d_in[3];
    const float* kw = (const float*)d_in[4];
    const float* kb = (const float*)d_in[5];
    const float* vw = (const float*)d_in[6];
    const float* vb = (const float*)d_in[7];
    const float* gm = (const float*)d_in[8];
    float* out = (float*)d_out;

    char* ws = (char*)d_ws;
    u16* qkv     = (u16*)(ws);                    // 41,943,040 B
    u16* qkvT    = (u16*)(ws + 41943040ull);      // 41,943,040 B
    u16* colT    = (u16*)(ws + 83886080ull);      // 33,554,432 B
    u16* colpart = qkvT;                          // alias: qkvT dead after k_col
    float* mH    = (float*)(ws + 117440512ull);   // 1,048,576 B
    float* sH    = (float*)(ws + 118489088ull);   // 1,048,576 B
    u16* wbf     = (u16*)(ws + 119537664ull);     // 20,480 B
    float* bias80= (float*)(ws + 119558144ull);   // 320 B
    u16* xybuf   = nullptr;                       // 33,554,432 B (optional)
    if (ws_size >= 119603200ull + 33554432ull)
        xybuf = (u16*)(ws + 119603200ull);

    k_wcvt<<<40, 256, 0, stream>>>(qw, qb, kw, kb, vw, vb, wbf, bias80);
    k_qkv_mfma<<<4096, 256, 0, stream>>>(x, y, wbf, bias80, qkv, xybuf);
    k_tr <<<5120, 256, 0, stream>>>(qkv, qkvT);          // 1280 planes
    k_col<<<2048, 512, 0, stream>>>(qkvT, colT, mH, sH);
    k_tr <<<4096, 256, 0, stream>>>(colT, colpart);      // 1024 planes
    k_row<<<2048, 512, 0, stream>>>(qkv, colpart, mH, sH, x, y, xybuf, gm, out);
}

// Round 5
// 180.726 us; speedup vs baseline: 4.6888x; 1.0709x over previous
//
#include <hip/hip_runtime.h>

#define NCH 80
#define HW 16384

typedef unsigned short u16;
typedef unsigned int u32;
typedef short s16x8 __attribute__((ext_vector_type(8)));
typedef float f32x4 __attribute__((ext_vector_type(4)));

__device__ __forceinline__ float b2f_lo(u32 pk){ union{u32 u; float f;} c; c.u = pk<<16; return c.f; }
__device__ __forceinline__ float b2f_hi(u32 pk){ union{u32 u; float f;} c; c.u = pk & 0xffff0000u; return c.f; }
__device__ __forceinline__ float b2f(u16 v){ union{u32 u; float f;} c; c.u = ((u32)v)<<16; return c.f; }
__device__ __forceinline__ u16 f2b_hw(float f){
    union{ __bf16 h; u16 s; } c; c.h = (__bf16)f; return c.s;
}
__device__ __forceinline__ u32 pk2(float a, float b){
    return (u32)f2b_hw(a) | ((u32)f2b_hw(b)<<16);
}
#define NEG_INF (-__builtin_inff())

union U4S8 { uint4 u; s16x8 v; };

// ---------------------------------------------------------------- P0: weight pack -> bf16
__global__ __launch_bounds__(256) void k_wcvt(
    const float* __restrict__ qw, const float* __restrict__ qb,
    const float* __restrict__ kw, const float* __restrict__ kb,
    const float* __restrict__ vw, const float* __restrict__ vb,
    u16* __restrict__ wbf, float* __restrict__ bias80)
{
    int i = blockIdx.x*256 + threadIdx.x;     // 0..10239
    int ch = i >> 7, cin = i & 127;
    float v;
    if (ch < 8)       v = (cin < 64) ? qw[ch*64 + cin] : 0.f;
    else if (ch < 16) v = (cin >= 64) ? kw[(ch-8)*64 + (cin-64)] : 0.f;
    else              v = vw[(ch-16)*128 + cin];
    wbf[i] = f2b_hw(v);
    if (i < 80){
        bias80[i] = (i<8) ? qb[i] : (i<16) ? kb[i-8] : vb[i-16];
    }
}

// ---------------------------------------------------------------- P1: qkv via MFMA, LDS-staged
// Block = 256 thr (4 waves), 128 pixels. Stage x,y as bf16 channel-pairs in LDS,
// then A-frags from LDS + B-frags (weights) from L1/L2.
__global__ __launch_bounds__(256, 4) void k_qkv_mfma(
    const float* __restrict__ x, const float* __restrict__ y,
    const u16* __restrict__ wbf, const float* __restrict__ bias80,
    u16* __restrict__ qkv, u16* __restrict__ xy)
{
    __shared__ u32 a32[128*65];   // [px][cp]; cp<32: x ch (2cp,2cp+1), cp>=32: y ch

    int t = threadIdx.x;
    int p0 = blockIdx.x * 128;
    int b = p0 >> 14, rem = p0 & 16383;
    const float* xb = x + (size_t)b*64*HW + rem;
    const float* yb = y + (size_t)b*64*HW + rem;

    // ---- stage: 8 iters x (2 float4 loads + 4 packed LDS writes)
    #pragma unroll
    for (int r=0;r<8;r++){
        int idx = t + r*256;          // 0..2047
        int cp = idx >> 5;            // 0..63
        int pxg = (idx & 31) * 4;
        const float* srcp = (cp < 32) ? xb : yb;
        int c0 = (cp & 31)*2;
        float4 fa = *(const float4*)&srcp[(size_t)c0*HW + pxg];
        float4 fb = *(const float4*)&srcp[(size_t)(c0+1)*HW + pxg];
        a32[(pxg+0)*65 + cp] = pk2(fa.x, fb.x);
        a32[(pxg+1)*65 + cp] = pk2(fa.y, fb.y);
        a32[(pxg+2)*65 + cp] = pk2(fa.z, fb.z);
        a32[(pxg+3)*65 + cp] = pk2(fa.w, fb.w);
    }
    __syncthreads();

    // ---- xy emit (bf16(x)+bf16(y), natural layout, coalesced u32 stores)
    if (xy){
        #pragma unroll
        for (int r=0;r<16;r++){
            int idx = t + r*256;      // 0..4095
            int c = idx >> 6;         // 0..63
            int pxp = idx & 63;       // pixel-pair
            int cpx = c >> 1, cpy = 32 + (c >> 1);
            u32 wx0 = a32[(2*pxp)*65 + cpx], wx1 = a32[(2*pxp+1)*65 + cpx];
            u32 wy0 = a32[(2*pxp)*65 + cpy], wy1 = a32[(2*pxp+1)*65 + cpy];
            float xv0 = (c&1)? b2f_hi(wx0) : b2f_lo(wx0);
            float xv1 = (c&1)? b2f_hi(wx1) : b2f_lo(wx1);
            float yv0 = (c&1)? b2f_hi(wy0) : b2f_lo(wy0);
            float yv1 = (c&1)? b2f_hi(wy1) : b2f_lo(wy1);
            size_t xw = ((size_t)(b*64+c)*HW + rem) >> 1;
            ((u32*)xy)[xw + pxp] = pk2(xv0+yv0, xv1+yv1);
        }
    }

    // ---- MFMA: wave wv owns m-tiles {2wv, 2wv+1} (32 px), 5 n-tiles, K=128
    int wv = t >> 6, l = t & 63;
    int lm = l & 15, lq = l >> 4;

    #pragma unroll
    for (int m2=0;m2<2;m2++){
        int pxl = (wv*2 + m2)*16 + lm;   // local pixel 0..127
        s16x8 af[4];
        #pragma unroll
        for (int ks=0;ks<4;ks++){
            int wbase = pxl*65 + ks*16 + lq*4;
            U4S8 uu;
            uu.u = make_uint4(a32[wbase], a32[wbase+1], a32[wbase+2], a32[wbase+3]);
            af[ks] = uu.v;
        }
        #pragma unroll
        for (int nt=0;nt<5;nt++){
            int ch = nt*16 + lm;
            const u16* wrow = wbf + ch*128 + lq*8;
            f32x4 acc = (f32x4){0.f,0.f,0.f,0.f};
            #pragma unroll
            for (int ks=0;ks<4;ks++){
                s16x8 bfrag = *(const s16x8*)(wrow + ks*32);
                acc = __builtin_amdgcn_mfma_f32_16x16x32_bf16(af[ks], bfrag, acc, 0, 0, 0);
            }
            float bs = bias80[ch];
            int pxs = (wv*2+m2)*16 + lq*4;
            u32 lo = pk2(acc[0]+bs, acc[1]+bs);
            u32 hi = pk2(acc[2]+bs, acc[3]+bs);
            *(uint2*)&qkv[(size_t)(b*NCH + ch)*HW + rem + pxs] = make_uint2(lo, hi);
        }
    }
}

// ------------------------------------------------ 128x128 bf16 plane transpose (unchanged)
__global__ __launch_bounds__(256) void k_tr(const u16* __restrict__ src, u16* __restrict__ dst)
{
    __shared__ u16 tile[64][65];
    int blk = blockIdx.x;
    int plane = blk >> 2, tq = blk & 3;
    int r0 = (tq >> 1) * 64, c0 = (tq & 1) * 64;
    const u16* s = src + (size_t)plane * HW;
    u16* d = dst + (size_t)plane * HW;
    int col = threadIdx.x & 63, rr = threadIdx.x >> 6;
    #pragma unroll
    for (int k=0;k<16;k++){
        int r = k*4 + rr;
        tile[r][col] = s[(r0+r)*128 + c0 + col];
    }
    __syncthreads();
    #pragma unroll
    for (int k=0;k<16;k++){
        int r = k*4 + rr;
        d[(c0+r)*128 + r0 + col] = tile[col][r];
    }
}

// ---------------------------------------------------------------- P2: column pass (MFMA PV)
__global__ __launch_bounds__(512, 4) void k_col(
    const u16* __restrict__ qkvT, u16* __restrict__ colT,
    float* __restrict__ mH, float* __restrict__ sH)
{
    __shared__ __align__(16) float q_s[8*128];    // [o][h]
    __shared__ __align__(16) float k_sw[8*128];   // [g][o^((g>>3)&7)]
    __shared__ __align__(16) u16  v_bf[64*128];   // [c][g], word ^ ((c&7)<<2)
    __shared__ __align__(16) u16  p_bf[128*128];  // [h][g], word ^ ((h&7)<<2)

    int t = threadIdx.x;
    int b = blockIdx.x >> 7, w = blockIdx.x & 127;
    const u32* src = (const u32*)(qkvT + (size_t)b*NCH*HW + w*128);
    u32* v32 = (u32*)v_bf;
    u32* p32 = (u32*)p_bf;

    #pragma unroll
    for (int r=0;r<2;r++){
        int idx = t + r*512;
        int ch = idx >> 6, hp = idx & 63;
        u32 pk = src[ch*8192 + hp];
        int g0 = hp*2;
        if (ch < 8){
            *(float2*)&q_s[ch*128 + g0] = make_float2(b2f_lo(pk), b2f_hi(pk));
        } else {
            int o = ch - 8;
            k_sw[g0*8     + (o ^ ((g0>>3)&7))]     = b2f_lo(pk);
            k_sw[(g0+1)*8 + (o ^ (((g0+1)>>3)&7))] = b2f_hi(pk);
        }
    }
    #pragma unroll
    for (int r=0;r<8;r++){
        int idx = t + r*512;
        int c = idx >> 6, gp = idx & 63;
        v32[(c*64 + gp) ^ ((c&7)<<2)] = src[(16+c)*8192 + gp];
    }
    __syncthreads();

    int tr = t >> 4, tc = t & 15;
    int h0 = tr*4, g0 = tc*8;
    float e[4][8];
    #pragma unroll
    for (int i=0;i<4;i++)
        #pragma unroll
        for (int j=0;j<8;j++) e[i][j] = 0.f;

    #pragma unroll
    for (int o=0;o<8;o++){
        float qv[4], kv[8];
        #pragma unroll
        for (int i=0;i<4;i++) qv[i] = q_s[o*128 + h0 + i];
        int kb = o ^ (tc & 7);
        #pragma unroll
        for (int j=0;j<8;j++) kv[j] = k_sw[(g0+j)*8 + kb];
        #pragma unroll
        for (int i=0;i<4;i++)
            #pragma unroll
            for (int j=0;j<8;j++) e[i][j] += qv[i]*kv[j];
    }
    #pragma unroll
    for (int i=0;i<4;i++){
        int h = h0 + i;
        if ((h>>3) == tc) e[i][h&7] = NEG_INF;
    }
    #pragma unroll
    for (int i=0;i<4;i++){
        int h = h0 + i;
        float m = e[i][0];
        #pragma unroll
        for (int j=1;j<8;j++) m = fmaxf(m, e[i][j]);
        m = fmaxf(m, __shfl_xor(m,1));
        m = fmaxf(m, __shfl_xor(m,2));
        m = fmaxf(m, __shfl_xor(m,4));
        m = fmaxf(m, __shfl_xor(m,8));
        float s = 0.f;
        #pragma unroll
        for (int j=0;j<8;j++){ float pp = __expf(e[i][j]-m); e[i][j]=pp; s += pp; }
        s += __shfl_xor(s,1);
        s += __shfl_xor(s,2);
        s += __shfl_xor(s,4);
        s += __shfl_xor(s,8);
        if (tc == 0){
            mH[b*HW + h*128 + w] = m;
            sH[b*HW + h*128 + w] = s;
        }
        uint4 pw;
        pw.x = pk2(e[i][0], e[i][1]);
        pw.y = pk2(e[i][2], e[i][3]);
        pw.z = pk2(e[i][4], e[i][5]);
        pw.w = pk2(e[i][6], e[i][7]);
        *(uint4*)&p32[(h*64 + tc*4) ^ ((h&7)<<2)] = pw;
    }
    __syncthreads();

    int wv = t >> 6, l = t & 63;
    int lm = l & 15, lq = l >> 4;
    int mt = wv;
    f32x4 acc[4];
    #pragma unroll
    for (int nt=0; nt<4; nt++) acc[nt] = (f32x4){0.f,0.f,0.f,0.f};

    #pragma unroll
    for (int ks=0; ks<4; ks++){
        int ri = mt*16 + lm;
        s16x8 a = *(const s16x8*)&p32[(ri*64 + ks*16 + lq*4) ^ ((ri&7)<<2)];
        #pragma unroll
        for (int nt=0; nt<4; nt++){
            int c = nt*16 + lm;
            s16x8 bf_ = *(const s16x8*)&v32[(c*64 + ks*16 + lq*4) ^ ((c&7)<<2)];
            acc[nt] = __builtin_amdgcn_mfma_f32_16x16x32_bf16(a, bf_, acc[nt], 0, 0, 0);
        }
    }
    #pragma unroll
    for (int nt=0; nt<4; nt++){
        int c = nt*16 + lm;
        int hh = mt*16 + lq*4;
        uint2 st;
        st.x = pk2(acc[nt][0], acc[nt][1]);
        st.y = pk2(acc[nt][2], acc[nt][3]);
        *(uint2*)&colT[((size_t)(b*64+c)*128 + w)*128 + hh] = st;
    }
}

// ---------------------------------------------------------------- P3: row pass + combine (MFMA PV)
__global__ __launch_bounds__(512, 4) void k_row(
    const u16* __restrict__ qkv, const u16* __restrict__ colpart,
    const float* __restrict__ mH, const float* __restrict__ sH,
    const float* __restrict__ x, const float* __restrict__ y,
    const u16* __restrict__ xy,
    const float* __restrict__ gamma_p, float* __restrict__ out)
{
    __shared__ __align__(16) float q_s[8*128];
    __shared__ __align__(16) float k_sw[8*128];
    __shared__ __align__(16) u16  v_bf[64*128];
    __shared__ __align__(16) u16  p_bf[128*128];
    __shared__ float fc_s[128], fr_s[128];

    int t = threadIdx.x;
    int b = blockIdx.x >> 7, h = blockIdx.x & 127;
    const u32* src = (const u32*)(qkv + (size_t)b*NCH*HW + h*128);
    u32* v32 = (u32*)v_bf;
    u32* p32 = (u32*)p_bf;

    #pragma unroll
    for (int r=0;r<2;r++){
        int idx = t + r*512;
        int ch = idx >> 6, wp = idx & 63;
        u32 pk = src[ch*8192 + wp];
        int u0 = wp*2;
        if (ch < 8){
            *(float2*)&q_s[ch*128 + u0] = make_float2(b2f_lo(pk), b2f_hi(pk));
        } else {
            int o = ch - 8;
            k_sw[u0*8     + (o ^ ((u0>>3)&7))]     = b2f_lo(pk);
            k_sw[(u0+1)*8 + (o ^ (((u0+1)>>3)&7))] = b2f_hi(pk);
        }
    }
    #pragma unroll
    for (int r=0;r<8;r++){
        int idx = t + r*512;
        int c = idx >> 6, up = idx & 63;
        v32[(c*64 + up) ^ ((c&7)<<2)] = src[(16+c)*8192 + up];
    }
    __syncthreads();

    int tr = t >> 4, tc = t & 15;
    int w0 = tr*4, u0 = tc*8;
    float e[4][8];
    #pragma unroll
    for (int i=0;i<4;i++)
        #pragma unroll
        for (int j=0;j<8;j++) e[i][j] = 0.f;

    #pragma unroll
    for (int o=0;o<8;o++){
        float qv[4], kv[8];
        #pragma unroll
        for (int i=0;i<4;i++) qv[i] = q_s[o*128 + w0 + i];
        int kb = o ^ (tc & 7);
        #pragma unroll
        for (int j=0;j<8;j++) kv[j] = k_sw[(u0+j)*8 + kb];
        #pragma unroll
        for (int i=0;i<4;i++)
            #pragma unroll
            for (int j=0;j<8;j++) e[i][j] += qv[i]*kv[j];
    }
    int pixbase = b*HW + h*128;
    #pragma unroll
    for (int i=0;i<4;i++){
        int wp = w0 + i;
        float m = e[i][0];
        #pragma unroll
        for (int j=1;j<8;j++) m = fmaxf(m, e[i][j]);
        m = fmaxf(m, __shfl_xor(m,1));
        m = fmaxf(m, __shfl_xor(m,2));
        m = fmaxf(m, __shfl_xor(m,4));
        m = fmaxf(m, __shfl_xor(m,8));
        float mh = mH[pixbase + wp];
        float sh = sH[pixbase + wp];
        float mg = fmaxf(m, mh);
        float s = 0.f;
        #pragma unroll
        for (int j=0;j<8;j++){ float pp = __expf(e[i][j]-mg); e[i][j]=pp; s += pp; }
        s += __shfl_xor(s,1);
        s += __shfl_xor(s,2);
        s += __shfl_xor(s,4);
        s += __shfl_xor(s,8);
        if (tc == 0){
            float ef = __expf(mh - mg);
            float stot = sh*ef + s;
            fc_s[wp] = ef/stot;
            fr_s[wp] = 1.0f/stot;
        }
        uint4 pw;
        pw.x = pk2(e[i][0], e[i][1]);
        pw.y = pk2(e[i][2], e[i][3]);
        pw.z = pk2(e[i][4], e[i][5]);
        pw.w = pk2(e[i][6], e[i][7]);
        *(uint4*)&p32[(wp*64 + tc*4) ^ ((wp&7)<<2)] = pw;
    }
    __syncthreads();

    int wv = t >> 6, l = t & 63;
    int lm = l & 15, lq = l >> 4;
    int mt = wv;
    f32x4 acc[4];
    #pragma unroll
    for (int nt=0; nt<4; nt++) acc[nt] = (f32x4){0.f,0.f,0.f,0.f};

    #pragma unroll
    for (int ks=0; ks<4; ks++){
        int ri = mt*16 + lm;
        s16x8 a = *(const s16x8*)&p32[(ri*64 + ks*16 + lq*4) ^ ((ri&7)<<2)];
        #pragma unroll
        for (int nt=0; nt<4; nt++){
            int c = nt*16 + lm;
            s16x8 bf_ = *(const s16x8*)&v32[(c*64 + ks*16 + lq*4) ^ ((c&7)<<2)];
            acc[nt] = __builtin_amdgcn_mfma_f32_16x16x32_bf16(a, bf_, acc[nt], 0, 0, 0);
        }
    }
    float gm = gamma_p[0];
    int wq0 = mt*16 + lq*4;
    float fcv[4], frv[4];
    #pragma unroll
    for (int r2=0;r2<4;r2++){ fcv[r2] = fc_s[wq0+r2]; frv[r2] = fr_s[wq0+r2]; }

    #pragma unroll
    for (int nt=0; nt<4; nt++){
        int c = nt*16 + lm;
        size_t off = ((size_t)(b*64+c)*128 + h)*128 + wq0;
        uint2 cpv = *(const uint2*)&colpart[off];
        float cp[4] = {b2f_lo(cpv.x), b2f_hi(cpv.x), b2f_lo(cpv.y), b2f_hi(cpv.y)};
        float xs[4];
        if (xy){
            uint2 xv = *(const uint2*)&xy[off];
            xs[0]=b2f_lo(xv.x); xs[1]=b2f_hi(xv.x); xs[2]=b2f_lo(xv.y); xs[3]=b2f_hi(xv.y);
        } else {
            float4 x4 = *(const float4*)&x[off];
            float4 y4 = *(const float4*)&y[off];
            xs[0]=x4.x+y4.x; xs[1]=x4.y+y4.y; xs[2]=x4.z+y4.z; xs[3]=x4.w+y4.w;
        }
        float4 o4;
        o4.x = gm*(cp[0]*fcv[0] + acc[nt][0]*frv[0]) + xs[0];
        o4.y = gm*(cp[1]*fcv[1] + acc[nt][1]*frv[1]) + xs[1];
        o4.z = gm*(cp[2]*fcv[2] + acc[nt][2]*frv[2]) + xs[2];
        o4.w = gm*(cp[3]*fcv[3] + acc[nt][3]*frv[3]) + xs[3];
        *(float4*)&out[off] = o4;
    }
}

// ----------------------------------------------------------------
extern "C" void kernel_launch(void* const* d_in, const int* in_sizes, int n_in,
                              void* d_out, int out_size, void* d_ws, size_t ws_size,
                              hipStream_t stream)
{
    (void)in_sizes; (void)n_in; (void)out_size;
    const float* x  = (const float*)d_in[0];
    const float* y  = (const float*)d_in[1];
    const float* qw = (const float*)d_in[2];
    const float* qb = (const float*)d_in[3];
    const float* kw = (const float*)d_in[4];
    const float* kb = (const float*)d_in[5];
    const float* vw = (const float*)d_in[6];
    const float* vb = (const float*)d_in[7];
    const float* gm = (const float*)d_in[8];
    float* out = (float*)d_out;

    char* ws = (char*)d_ws;
    u16* qkv     = (u16*)(ws);                    // 41,943,040 B
    u16* qkvT    = (u16*)(ws + 41943040ull);      // 41,943,040 B
    u16* colT    = (u16*)(ws + 83886080ull);      // 33,554,432 B
    u16* colpart = qkvT;                          // alias: qkvT dead after k_col
    float* mH    = (float*)(ws + 117440512ull);   // 1,048,576 B
    float* sH    = (float*)(ws + 118489088ull);   // 1,048,576 B
    u16* wbf     = (u16*)(ws + 119537664ull);     // 20,480 B
    float* bias80= (float*)(ws + 119558144ull);   // 320 B
    u16* xybuf   = nullptr;                       // 33,554,432 B (optional)
    if (ws_size >= 119603200ull + 33554432ull)
        xybuf = (u16*)(ws + 119603200ull);

    k_wcvt<<<40, 256, 0, stream>>>(qw, qb, kw, kb, vw, vb, wbf, bias80);
    k_qkv_mfma<<<2048, 256, 0, stream>>>(x, y, wbf, bias80, qkv, xybuf);
    k_tr <<<5120, 256, 0, stream>>>(qkv, qkvT);          // 1280 planes
    k_col<<<2048, 512, 0, stream>>>(qkvT, colT, mH, sH);
    k_tr <<<4096, 256, 0, stream>>>(colT, colpart);      // 1024 planes
    k_row<<<2048, 512, 0, stream>>>(qkv, colpart, mH, sH, x, y, xybuf, gm, out);
}

// Round 6
// 165.484 us; speedup vs baseline: 5.1207x; 1.0921x over previous
//
#include <hip/hip_runtime.h>

#define NCH 80
#define HW 16384

typedef unsigned short u16;
typedef unsigned int u32;
typedef short s16x8 __attribute__((ext_vector_type(8)));
typedef float f32x4 __attribute__((ext_vector_type(4)));

__device__ __forceinline__ float b2f_lo(u32 pk){ union{u32 u; float f;} c; c.u = pk<<16; return c.f; }
__device__ __forceinline__ float b2f_hi(u32 pk){ union{u32 u; float f;} c; c.u = pk & 0xffff0000u; return c.f; }
__device__ __forceinline__ float b2f(u16 v){ union{u32 u; float f;} c; c.u = ((u32)v)<<16; return c.f; }
__device__ __forceinline__ u16 f2b_hw(float f){
    union{ __bf16 h; u16 s; } c; c.h = (__bf16)f; return c.s;
}
__device__ __forceinline__ u32 pk2(float a, float b){
    return (u32)f2b_hw(a) | ((u32)f2b_hw(b)<<16);
}
#define NEG_INF (-__builtin_inff())

union U4S8 { uint4 u; s16x8 v; };

// ---------------------------------------------------------------- P0: weight pack -> bf16
__global__ __launch_bounds__(256) void k_wcvt(
    const float* __restrict__ qw, const float* __restrict__ qb,
    const float* __restrict__ kw, const float* __restrict__ kb,
    const float* __restrict__ vw, const float* __restrict__ vb,
    u16* __restrict__ wbf, float* __restrict__ bias80)
{
    int i = blockIdx.x*256 + threadIdx.x;     // 0..10239
    int ch = i >> 7, cin = i & 127;
    float v;
    if (ch < 8)       v = (cin < 64) ? qw[ch*64 + cin] : 0.f;
    else if (ch < 16) v = (cin >= 64) ? kw[(ch-8)*64 + (cin-64)] : 0.f;
    else              v = vw[(ch-16)*128 + cin];
    wbf[i] = f2b_hw(v);
    if (i < 80){
        bias80[i] = (i<8) ? qb[i] : (i<16) ? kb[i-8] : vb[i-16];
    }
}

// ---------------------------------------------------------------- P1: qkv via MFMA, high-MLP staging
// Block = 256 thr (4 waves), 128 pixels. Phase A: 16 float4 loads ALL in flight,
// then convert -> LDS [cp][px] + fused xy emit. Phase B: MFMA vs L1-resident weights.
__global__ __launch_bounds__(256) void k_qkv_mfma(
    const float* __restrict__ x, const float* __restrict__ y,
    const u16* __restrict__ wbf, const float* __restrict__ bias80,
    u16* __restrict__ qkv, u16* __restrict__ xy)
{
    // a32[cp][px]: cp<32 -> x channel-pair (2cp,2cp+1); cp>=32 -> y channel-pair.
    // row stride 132 u32 (pad 4) -> b128 aligned writes, 2-way read conflicts.
    __shared__ u32 a32[64*132];

    int t = threadIdx.x;
    int p0 = blockIdx.x * 128;
    int b = p0 >> 14, rem = p0 & 16383;
    const float* xb = x + (size_t)b*64*HW + rem;
    const float* yb = y + (size_t)b*64*HW + rem;

    // ---- Phase A1: issue ALL 16 loads (no LDS dependency in between)
    float4 fx0[4], fx1[4], fy0[4], fy1[4];
    #pragma unroll
    for (int r=0;r<4;r++){
        int idx = t + r*256;              // 0..1023
        int cp = idx >> 5;                // 0..31 channel-pair
        int pxg = (idx & 31) * 4;         // pixel group base
        const float* xp = xb + (size_t)(2*cp)*HW + pxg;
        const float* yp = yb + (size_t)(2*cp)*HW + pxg;
        fx0[r] = *(const float4*)xp;
        fx1[r] = *(const float4*)(xp + HW);
        fy0[r] = *(const float4*)yp;
        fy1[r] = *(const float4*)(yp + HW);
    }
    // ---- Phase A2: convert + LDS + fused xy emit
    #pragma unroll
    for (int r=0;r<4;r++){
        int idx = t + r*256;
        int cp = idx >> 5;
        int pxg = (idx & 31) * 4;
        uint4 wx, wy;
        wx.x = pk2(fx0[r].x, fx1[r].x);
        wx.y = pk2(fx0[r].y, fx1[r].y);
        wx.z = pk2(fx0[r].z, fx1[r].z);
        wx.w = pk2(fx0[r].w, fx1[r].w);
        wy.x = pk2(fy0[r].x, fy1[r].x);
        wy.y = pk2(fy0[r].y, fy1[r].y);
        wy.z = pk2(fy0[r].z, fy1[r].z);
        wy.w = pk2(fy0[r].w, fy1[r].w);
        *(uint4*)&a32[cp*132 + pxg]       = wx;
        *(uint4*)&a32[(32+cp)*132 + pxg]  = wy;
        if (xy){
            uint2 s0, s1;
            s0.x = pk2(fx0[r].x+fy0[r].x, fx0[r].y+fy0[r].y);
            s0.y = pk2(fx0[r].z+fy0[r].z, fx0[r].w+fy0[r].w);
            s1.x = pk2(fx1[r].x+fy1[r].x, fx1[r].y+fy1[r].y);
            s1.y = pk2(fx1[r].z+fy1[r].z, fx1[r].w+fy1[r].w);
            *(uint2*)&xy[(size_t)(b*64 + 2*cp)*HW + rem + pxg]     = s0;
            *(uint2*)&xy[(size_t)(b*64 + 2*cp+1)*HW + rem + pxg]   = s1;
        }
    }
    __syncthreads();

    // ---- Phase B: MFMA. Wave wv owns pixels [(2wv)*16, (2wv+2)*16), 5 n-tiles.
    int wv = t >> 6, l = t & 63;
    int lm = l & 15, lq = l >> 4;

    // A-fragments for both m-tiles: af[m2][ks], lane lm = pixel, k = ks*32+lq*8+j
    s16x8 af[2][4];
    #pragma unroll
    for (int m2=0;m2<2;m2++){
        int pxl = (wv*2 + m2)*16 + lm;
        #pragma unroll
        for (int ks=0;ks<4;ks++){
            int cpb = (ks&1)*16 + lq*4 + ((ks>>1)*32);   // cp row: x: ks*16, y: 32+(ks-2)*16
            U4S8 uu;
            uu.u = make_uint4(a32[(cpb+0)*132 + pxl], a32[(cpb+1)*132 + pxl],
                              a32[(cpb+2)*132 + pxl], a32[(cpb+3)*132 + pxl]);
            af[m2][ks] = uu.v;
        }
    }

    #pragma unroll
    for (int nt=0;nt<5;nt++){
        int ch = nt*16 + lm;
        const u16* wrow = wbf + ch*128 + lq*8;
        s16x8 b0 = *(const s16x8*)(wrow);
        s16x8 b1 = *(const s16x8*)(wrow + 32);
        s16x8 b2 = *(const s16x8*)(wrow + 64);
        s16x8 b3 = *(const s16x8*)(wrow + 96);
        f32x4 acc0 = (f32x4){0.f,0.f,0.f,0.f};
        f32x4 acc1 = (f32x4){0.f,0.f,0.f,0.f};
        acc0 = __builtin_amdgcn_mfma_f32_16x16x32_bf16(af[0][0], b0, acc0, 0,0,0);
        acc1 = __builtin_amdgcn_mfma_f32_16x16x32_bf16(af[1][0], b0, acc1, 0,0,0);
        acc0 = __builtin_amdgcn_mfma_f32_16x16x32_bf16(af[0][1], b1, acc0, 0,0,0);
        acc1 = __builtin_amdgcn_mfma_f32_16x16x32_bf16(af[1][1], b1, acc1, 0,0,0);
        acc0 = __builtin_amdgcn_mfma_f32_16x16x32_bf16(af[0][2], b2, acc0, 0,0,0);
        acc1 = __builtin_amdgcn_mfma_f32_16x16x32_bf16(af[1][2], b2, acc1, 0,0,0);
        acc0 = __builtin_amdgcn_mfma_f32_16x16x32_bf16(af[0][3], b3, acc0, 0,0,0);
        acc1 = __builtin_amdgcn_mfma_f32_16x16x32_bf16(af[1][3], b3, acc1, 0,0,0);
        float bs = bias80[ch];
        size_t chbase = (size_t)(b*NCH + ch)*HW + rem;
        uint2 st0, st1;
        st0.x = pk2(acc0[0]+bs, acc0[1]+bs);
        st0.y = pk2(acc0[2]+bs, acc0[3]+bs);
        st1.x = pk2(acc1[0]+bs, acc1[1]+bs);
        st1.y = pk2(acc1[2]+bs, acc1[3]+bs);
        *(uint2*)&qkv[chbase + (wv*2+0)*16 + lq*4] = st0;
        *(uint2*)&qkv[chbase + (wv*2+1)*16 + lq*4] = st1;
    }
}

// ------------------------------------------------ 128x128 bf16 plane transpose (unchanged)
__global__ __launch_bounds__(256) void k_tr(const u16* __restrict__ src, u16* __restrict__ dst)
{
    __shared__ u16 tile[64][65];
    int blk = blockIdx.x;
    int plane = blk >> 2, tq = blk & 3;
    int r0 = (tq >> 1) * 64, c0 = (tq & 1) * 64;
    const u16* s = src + (size_t)plane * HW;
    u16* d = dst + (size_t)plane * HW;
    int col = threadIdx.x & 63, rr = threadIdx.x >> 6;
    #pragma unroll
    for (int k=0;k<16;k++){
        int r = k*4 + rr;
        tile[r][col] = s[(r0+r)*128 + c0 + col];
    }
    __syncthreads();
    #pragma unroll
    for (int k=0;k<16;k++){
        int r = k*4 + rr;
        d[(c0+r)*128 + r0 + col] = tile[col][r];
    }
}

// ---------------------------------------------------------------- P2: column pass (MFMA PV)
__global__ __launch_bounds__(512, 4) void k_col(
    const u16* __restrict__ qkvT, u16* __restrict__ colT,
    float* __restrict__ mH, float* __restrict__ sH)
{
    __shared__ __align__(16) float q_s[8*128];    // [o][h]
    __shared__ __align__(16) float k_sw[8*128];   // [g][o^((g>>3)&7)]
    __shared__ __align__(16) u16  v_bf[64*128];   // [c][g], word ^ ((c&7)<<2)
    __shared__ __align__(16) u16  p_bf[128*128];  // [h][g], word ^ ((h&7)<<2)

    int t = threadIdx.x;
    int b = blockIdx.x >> 7, w = blockIdx.x & 127;
    const u32* src = (const u32*)(qkvT + (size_t)b*NCH*HW + w*128);
    u32* v32 = (u32*)v_bf;
    u32* p32 = (u32*)p_bf;

    #pragma unroll
    for (int r=0;r<2;r++){
        int idx = t + r*512;
        int ch = idx >> 6, hp = idx & 63;
        u32 pk = src[ch*8192 + hp];
        int g0 = hp*2;
        if (ch < 8){
            *(float2*)&q_s[ch*128 + g0] = make_float2(b2f_lo(pk), b2f_hi(pk));
        } else {
            int o = ch - 8;
            k_sw[g0*8     + (o ^ ((g0>>3)&7))]     = b2f_lo(pk);
            k_sw[(g0+1)*8 + (o ^ (((g0+1)>>3)&7))] = b2f_hi(pk);
        }
    }
    #pragma unroll
    for (int r=0;r<8;r++){
        int idx = t + r*512;
        int c = idx >> 6, gp = idx & 63;
        v32[(c*64 + gp) ^ ((c&7)<<2)] = src[(16+c)*8192 + gp];
    }
    __syncthreads();

    int tr = t >> 4, tc = t & 15;
    int h0 = tr*4, g0 = tc*8;
    float e[4][8];
    #pragma unroll
    for (int i=0;i<4;i++)
        #pragma unroll
        for (int j=0;j<8;j++) e[i][j] = 0.f;

    #pragma unroll
    for (int o=0;o<8;o++){
        float qv[4], kv[8];
        #pragma unroll
        for (int i=0;i<4;i++) qv[i] = q_s[o*128 + h0 + i];
        int kb = o ^ (tc & 7);
        #pragma unroll
        for (int j=0;j<8;j++) kv[j] = k_sw[(g0+j)*8 + kb];
        #pragma unroll
        for (int i=0;i<4;i++)
            #pragma unroll
            for (int j=0;j<8;j++) e[i][j] += qv[i]*kv[j];
    }
    #pragma unroll
    for (int i=0;i<4;i++){
        int h = h0 + i;
        if ((h>>3) == tc) e[i][h&7] = NEG_INF;
    }
    #pragma unroll
    for (int i=0;i<4;i++){
        int h = h0 + i;
        float m = e[i][0];
        #pragma unroll
        for (int j=1;j<8;j++) m = fmaxf(m, e[i][j]);
        m = fmaxf(m, __shfl_xor(m,1));
        m = fmaxf(m, __shfl_xor(m,2));
        m = fmaxf(m, __shfl_xor(m,4));
        m = fmaxf(m, __shfl_xor(m,8));
        float s = 0.f;
        #pragma unroll
        for (int j=0;j<8;j++){ float pp = __expf(e[i][j]-m); e[i][j]=pp; s += pp; }
        s += __shfl_xor(s,1);
        s += __shfl_xor(s,2);
        s += __shfl_xor(s,4);
        s += __shfl_xor(s,8);
        if (tc == 0){
            mH[b*HW + h*128 + w] = m;
            sH[b*HW + h*128 + w] = s;
        }
        uint4 pw;
        pw.x = pk2(e[i][0], e[i][1]);
        pw.y = pk2(e[i][2], e[i][3]);
        pw.z = pk2(e[i][4], e[i][5]);
        pw.w = pk2(e[i][6], e[i][7]);
        *(uint4*)&p32[(h*64 + tc*4) ^ ((h&7)<<2)] = pw;
    }
    __syncthreads();

    int wv = t >> 6, l = t & 63;
    int lm = l & 15, lq = l >> 4;
    int mt = wv;
    f32x4 acc[4];
    #pragma unroll
    for (int nt=0; nt<4; nt++) acc[nt] = (f32x4){0.f,0.f,0.f,0.f};

    #pragma unroll
    for (int ks=0; ks<4; ks++){
        int ri = mt*16 + lm;
        s16x8 a = *(const s16x8*)&p32[(ri*64 + ks*16 + lq*4) ^ ((ri&7)<<2)];
        #pragma unroll
        for (int nt=0; nt<4; nt++){
            int c = nt*16 + lm;
            s16x8 bf_ = *(const s16x8*)&v32[(c*64 + ks*16 + lq*4) ^ ((c&7)<<2)];
            acc[nt] = __builtin_amdgcn_mfma_f32_16x16x32_bf16(a, bf_, acc[nt], 0, 0, 0);
        }
    }
    #pragma unroll
    for (int nt=0; nt<4; nt++){
        int c = nt*16 + lm;
        int hh = mt*16 + lq*4;
        uint2 st;
        st.x = pk2(acc[nt][0], acc[nt][1]);
        st.y = pk2(acc[nt][2], acc[nt][3]);
        *(uint2*)&colT[((size_t)(b*64+c)*128 + w)*128 + hh] = st;
    }
}

// ---------------------------------------------------------------- P3: row pass + combine (MFMA PV)
__global__ __launch_bounds__(512, 4) void k_row(
    const u16* __restrict__ qkv, const u16* __restrict__ colpart,
    const float* __restrict__ mH, const float* __restrict__ sH,
    const float* __restrict__ x, const float* __restrict__ y,
    const u16* __restrict__ xy,
    const float* __restrict__ gamma_p, float* __restrict__ out)
{
    __shared__ __align__(16) float q_s[8*128];
    __shared__ __align__(16) float k_sw[8*128];
    __shared__ __align__(16) u16  v_bf[64*128];
    __shared__ __align__(16) u16  p_bf[128*128];
    __shared__ float fc_s[128], fr_s[128];

    int t = threadIdx.x;
    int b = blockIdx.x >> 7, h = blockIdx.x & 127;
    const u32* src = (const u32*)(qkv + (size_t)b*NCH*HW + h*128);
    u32* v32 = (u32*)v_bf;
    u32* p32 = (u32*)p_bf;

    #pragma unroll
    for (int r=0;r<2;r++){
        int idx = t + r*512;
        int ch = idx >> 6, wp = idx & 63;
        u32 pk = src[ch*8192 + wp];
        int u0 = wp*2;
        if (ch < 8){
            *(float2*)&q_s[ch*128 + u0] = make_float2(b2f_lo(pk), b2f_hi(pk));
        } else {
            int o = ch - 8;
            k_sw[u0*8     + (o ^ ((u0>>3)&7))]     = b2f_lo(pk);
            k_sw[(u0+1)*8 + (o ^ (((u0+1)>>3)&7))] = b2f_hi(pk);
        }
    }
    #pragma unroll
    for (int r=0;r<8;r++){
        int idx = t + r*512;
        int c = idx >> 6, up = idx & 63;
        v32[(c*64 + up) ^ ((c&7)<<2)] = src[(16+c)*8192 + up];
    }
    __syncthreads();

    int tr = t >> 4, tc = t & 15;
    int w0 = tr*4, u0 = tc*8;
    float e[4][8];
    #pragma unroll
    for (int i=0;i<4;i++)
        #pragma unroll
        for (int j=0;j<8;j++) e[i][j] = 0.f;

    #pragma unroll
    for (int o=0;o<8;o++){
        float qv[4], kv[8];
        #pragma unroll
        for (int i=0;i<4;i++) qv[i] = q_s[o*128 + w0 + i];
        int kb = o ^ (tc & 7);
        #pragma unroll
        for (int j=0;j<8;j++) kv[j] = k_sw[(u0+j)*8 + kb];
        #pragma unroll
        for (int i=0;i<4;i++)
            #pragma unroll
            for (int j=0;j<8;j++) e[i][j] += qv[i]*kv[j];
    }
    int pixbase = b*HW + h*128;
    #pragma unroll
    for (int i=0;i<4;i++){
        int wp = w0 + i;
        float m = e[i][0];
        #pragma unroll
        for (int j=1;j<8;j++) m = fmaxf(m, e[i][j]);
        m = fmaxf(m, __shfl_xor(m,1));
        m = fmaxf(m, __shfl_xor(m,2));
        m = fmaxf(m, __shfl_xor(m,4));
        m = fmaxf(m, __shfl_xor(m,8));
        float mh = mH[pixbase + wp];
        float sh = sH[pixbase + wp];
        float mg = fmaxf(m, mh);
        float s = 0.f;
        #pragma unroll
        for (int j=0;j<8;j++){ float pp = __expf(e[i][j]-mg); e[i][j]=pp; s += pp; }
        s += __shfl_xor(s,1);
        s += __shfl_xor(s,2);
        s += __shfl_xor(s,4);
        s += __shfl_xor(s,8);
        if (tc == 0){
            float ef = __expf(mh - mg);
            float stot = sh*ef + s;
            fc_s[wp] = ef/stot;
            fr_s[wp] = 1.0f/stot;
        }
        uint4 pw;
        pw.x = pk2(e[i][0], e[i][1]);
        pw.y = pk2(e[i][2], e[i][3]);
        pw.z = pk2(e[i][4], e[i][5]);
        pw.w = pk2(e[i][6], e[i][7]);
        *(uint4*)&p32[(wp*64 + tc*4) ^ ((wp&7)<<2)] = pw;
    }
    __syncthreads();

    int wv = t >> 6, l = t & 63;
    int lm = l & 15, lq = l >> 4;
    int mt = wv;
    f32x4 acc[4];
    #pragma unroll
    for (int nt=0; nt<4; nt++) acc[nt] = (f32x4){0.f,0.f,0.f,0.f};

    #pragma unroll
    for (int ks=0; ks<4; ks++){
        int ri = mt*16 + lm;
        s16x8 a = *(const s16x8*)&p32[(ri*64 + ks*16 + lq*4) ^ ((ri&7)<<2)];
        #pragma unroll
        for (int nt=0; nt<4; nt++){
            int c = nt*16 + lm;
            s16x8 bf_ = *(const s16x8*)&v32[(c*64 + ks*16 + lq*4) ^ ((c&7)<<2)];
            acc[nt] = __builtin_amdgcn_mfma_f32_16x16x32_bf16(a, bf_, acc[nt], 0, 0, 0);
        }
    }
    float gm = gamma_p[0];
    int wq0 = mt*16 + lq*4;
    float fcv[4], frv[4];
    #pragma unroll
    for (int r2=0;r2<4;r2++){ fcv[r2] = fc_s[wq0+r2]; frv[r2] = fr_s[wq0+r2]; }

    #pragma unroll
    for (int nt=0; nt<4; nt++){
        int c = nt*16 + lm;
        size_t off = ((size_t)(b*64+c)*128 + h)*128 + wq0;
        uint2 cpv = *(const uint2*)&colpart[off];
        float cp[4] = {b2f_lo(cpv.x), b2f_hi(cpv.x), b2f_lo(cpv.y), b2f_hi(cpv.y)};
        float xs[4];
        if (xy){
            uint2 xv = *(const uint2*)&xy[off];
            xs[0]=b2f_lo(xv.x); xs[1]=b2f_hi(xv.x); xs[2]=b2f_lo(xv.y); xs[3]=b2f_hi(xv.y);
        } else {
            float4 x4 = *(const float4*)&x[off];
            float4 y4 = *(const float4*)&y[off];
            xs[0]=x4.x+y4.x; xs[1]=x4.y+y4.y; xs[2]=x4.z+y4.z; xs[3]=x4.w+y4.w;
        }
        float4 o4;
        o4.x = gm*(cp[0]*fcv[0] + acc[nt][0]*frv[0]) + xs[0];
        o4.y = gm*(cp[1]*fcv[1] + acc[nt][1]*frv[1]) + xs[1];
        o4.z = gm*(cp[2]*fcv[2] + acc[nt][2]*frv[2]) + xs[2];
        o4.w = gm*(cp[3]*fcv[3] + acc[nt][3]*frv[3]) + xs[3];
        *(float4*)&out[off] = o4;
    }
}

// ----------------------------------------------------------------
extern "C" void kernel_launch(void* const* d_in, const int* in_sizes, int n_in,
                              void* d_out, int out_size, void* d_ws, size_t ws_size,
                              hipStream_t stream)
{
    (void)in_sizes; (void)n_in; (void)out_size;
    const float* x  = (const float*)d_in[0];
    const float* y  = (const float*)d_in[1];
    const float* qw = (const float*)d_in[2];
    const float* qb = (const float*)d_in[3];
    const float* kw = (const float*)d_in[4];
    const float* kb = (const float*)d_in[5];
    const float* vw = (const float*)d_in[6];
    const float* vb = (const float*)d_in[7];
    const float* gm = (const float*)d_in[8];
    float* out = (float*)d_out;

    char* ws = (char*)d_ws;
    u16* qkv     = (u16*)(ws);                    // 41,943,040 B
    u16* qkvT    = (u16*)(ws + 41943040ull);      // 41,943,040 B
    u16* colT    = (u16*)(ws + 83886080ull);      // 33,554,432 B
    u16* colpart = qkvT;                          // alias: qkvT dead after k_col
    float* mH    = (float*)(ws + 117440512ull);   // 1,048,576 B
    float* sH    = (float*)(ws + 118489088ull);   // 1,048,576 B
    u16* wbf     = (u16*)(ws + 119537664ull);     // 20,480 B
    float* bias80= (float*)(ws + 119558144ull);   // 320 B
    u16* xybuf   = nullptr;                       // 33,554,432 B (optional)
    if (ws_size >= 119603200ull + 33554432ull)
        xybuf = (u16*)(ws + 119603200ull);

    k_wcvt<<<40, 256, 0, stream>>>(qw, qb, kw, kb, vw, vb, wbf, bias80);
    k_qkv_mfma<<<2048, 256, 0, stream>>>(x, y, wbf, bias80, qkv, xybuf);
    k_tr <<<5120, 256, 0, stream>>>(qkv, qkvT);          // 1280 planes
    k_col<<<2048, 512, 0, stream>>>(qkvT, colT, mH, sH);
    k_tr <<<4096, 256, 0, stream>>>(colT, colpart);      // 1024 planes
    k_row<<<2048, 512, 0, stream>>>(qkv, colpart, mH, sH, x, y, xybuf, gm, out);
}